// Round 18
// baseline (148.876 us; speedup 1.0000x reference)
//
#include <hip/hip_runtime.h>

// LocalTopKCrossReadout: B=8, Lq=1024 (16 steps x 64), Lkv=4096 (64 x 64),
// DIM=512, WINDOW=2 (<=5 steps = 320 cols), TOPK=32.
#define NWIN 320
#define SCORE_SCALE 0.04419417382415922f  // 1/sqrt(512)

__constant__ int CENTERS[16] = {0,4,8,13,17,21,25,29,34,38,42,46,50,55,59,63};

typedef __attribute__((ext_vector_type(8))) short v8s;   // 8 bf16
typedef __attribute__((ext_vector_type(4))) float v4f;   // 4 f32 acc

__device__ __forceinline__ float bflo(unsigned u) { return __uint_as_float(u << 16); }
__device__ __forceinline__ float bfhi(unsigned u) { return __uint_as_float(u & 0xffff0000u); }
__device__ __forceinline__ float bf2f(unsigned short h) { return __uint_as_float(((unsigned)h) << 16); }
__device__ __forceinline__ unsigned short f2bf(float x) {
  unsigned u = __float_as_uint(x);
  unsigned r = 0x7fffu + ((u >> 16) & 1u);   // RNE
  return (unsigned short)((u + r) >> 16);
}

// ---- T64 tile: 64 rows x 32 k bf16 in 4096 B, XOR-swizzled for conflict-free b128 ----
__device__ __forceinline__ int t64_off(int r, int k) {
  return ((r & 31) << 7) + (((((r >> 5) << 2) | (k >> 3)) ^ (r & 7)) << 4) + ((k & 7) << 1);
}
__device__ __forceinline__ int frag_off(int r, int g) {
  return ((r & 31) << 7) + (((((r >> 5) << 2) | g) ^ (r & 7)) << 4);
}

__device__ __forceinline__ void gload_lds16(const void* g, void* l) {
  __builtin_amdgcn_global_load_lds((const __attribute__((address_space(1))) unsigned int*)g,
                                   (__attribute__((address_space(3))) unsigned int*)l, 16, 0, 0);
}

// pack 8 f32 -> hi-bf16 plane AND lo-residual plane in one shot
__device__ __forceinline__ void cvt8pair(float4 a, float4 b, uint4& hi4, uint4& lo4) {
  float v[8] = {a.x, a.y, a.z, a.w, b.x, b.y, b.z, b.w};
  unsigned short h[8], l[8];
  #pragma unroll
  for (int e = 0; e < 8; ++e) {
    h[e] = f2bf(v[e]);
    l[e] = f2bf(v[e] - bf2f(h[e]));
  }
  hi4.x = (unsigned)h[0] | ((unsigned)h[1] << 16);
  hi4.y = (unsigned)h[2] | ((unsigned)h[3] << 16);
  hi4.z = (unsigned)h[4] | ((unsigned)h[5] << 16);
  hi4.w = (unsigned)h[6] | ((unsigned)h[7] << 16);
  lo4.x = (unsigned)l[0] | ((unsigned)l[1] << 16);
  lo4.y = (unsigned)l[2] | ((unsigned)l[3] << 16);
  lo4.z = (unsigned)l[4] | ((unsigned)l[5] << 16);
  lo4.w = (unsigned)l[6] | ((unsigned)l[7] << 16);
}

__device__ __forceinline__ uint4 cvt8hi(float4 a, float4 b) {
  uint4 r;
  r.x = (unsigned)f2bf(a.x) | ((unsigned)f2bf(a.y) << 16);
  r.y = (unsigned)f2bf(a.z) | ((unsigned)f2bf(a.w) << 16);
  r.z = (unsigned)f2bf(b.x) | ((unsigned)f2bf(b.y) << 16);
  r.w = (unsigned)f2bf(b.z) | ((unsigned)f2bf(b.w) << 16);
  return r;
}

__device__ __forceinline__ uint2 cvt4(float4 a) {
  uint2 r;
  r.x = (unsigned)f2bf(a.x) | ((unsigned)f2bf(a.y) << 16);
  r.y = (unsigned)f2bf(a.z) | ((unsigned)f2bf(a.w) << 16);
  return r;
}

// ================= prep1: film_part + u + wsplit + wconv (fused, 256 thr) =========
__global__ __launch_bounds__(256) void prep1_kernel(
    const float* __restrict__ ctx1, const float* __restrict__ ctx2,
    const float* __restrict__ Wc,  float* __restrict__ part,
    const float* __restrict__ Wk,  const float* __restrict__ bq, float* __restrict__ u,
    const float* __restrict__ Wq,
    unsigned short* __restrict__ Wqh, unsigned short* __restrict__ Wql,
    unsigned short* __restrict__ Wkh, unsigned short* __restrict__ Wkl,
    const float* __restrict__ Wv, const float* __restrict__ Wo,
    unsigned short* __restrict__ Wvt, unsigned short* __restrict__ Wot)
{
  __shared__ char img[32768];
  const int bid = blockIdx.x;
  const int tid = threadIdx.x;

  if (bid < 256) {
    // ---- film_part: b(8) x sl(8) x jq(4) ----
    const int b = bid >> 5, sl = (bid >> 2) & 7, jq = bid & 3;
    const int j = jq * 256 + tid;
    const int i0 = sl * 128;
    float acc = 0.f;
    #pragma unroll 4
    for (int t = 0; t < 128; ++t) {
      const int i = i0 + t;
      const float f = (i < 512) ? ctx1[b * 512 + i] : ctx2[b * 512 + i - 512];
      acc = fmaf(f, Wc[(size_t)i * 1024 + j], acc);
    }
    part[(b * 8 + sl) * 1024 + j] = acc;
  } else if (bid < 384) {
    // ---- u = (Wk . bq) * scale: 4 d per block (one per wave) ----
    const int d = (bid - 256) * 4 + (tid >> 6);
    const int lane = tid & 63;
    float4 a0 = *(const float4*)&Wk[(size_t)d * 512 + lane * 8];
    float4 a1 = *(const float4*)&Wk[(size_t)d * 512 + lane * 8 + 4];
    float4 c0 = *(const float4*)&bq[lane * 8];
    float4 c1 = *(const float4*)&bq[lane * 8 + 4];
    float s = a0.x*c0.x + a0.y*c0.y + a0.z*c0.z + a0.w*c0.w
            + a1.x*c1.x + a1.y*c1.y + a1.z*c1.z + a1.w*c1.w;
    #pragma unroll
    for (int off = 32; off > 0; off >>= 1) s += __shfl_xor(s, off, 64);
    if (lane == 0) u[d] = s * SCORE_SCALE;
  } else if (bid < 640) {
    // ---- wsplit: Wq/Wk -> row-major bf16 hi/lo planes ----
    const int b = bid - 384;          // 0..255
    const int mat = b >> 7;
    const float* Wsrc = mat ? Wk : Wq;
    unsigned short* Wh = mat ? Wkh : Wqh;
    unsigned short* Wl = mat ? Wkl : Wql;
    const size_t e0 = (((size_t)(b & 127) * 256) + tid) * 8;
    float4 x0 = *(const float4*)&Wsrc[e0];
    float4 x1 = *(const float4*)&Wsrc[e0 + 4];
    uint4 h4, l4;
    cvt8pair(x0, x1, h4, l4);
    *(uint4*)&Wh[e0] = h4;
    *(uint4*)&Wl[e0] = l4;
  } else {
    // ---- wconv: Wv/Wo -> T64 hi tiles (W^T layout) ----
    const int cb = bid - 640;         // 0..31
    const int ktile = cb & 15;
    const int mat   = cb >> 4;
    const float* W = mat ? Wo : Wv;
    unsigned short* Dt = mat ? Wot : Wvt;
    const int k  = tid >> 3;
    const int nt = tid & 7;
    #pragma unroll
    for (int e4 = 0; e4 < 16; ++e4) {
      float4 w = *(const float4*)&W[(size_t)(ktile * 32 + k) * 512 + nt * 64 + e4 * 4];
      float vv[4] = {w.x, w.y, w.z, w.w};
      #pragma unroll
      for (int c = 0; c < 4; ++c) {
        const int n = e4 * 4 + c;
        *(unsigned short*)(img + nt * 4096 + t64_off(n, k)) = f2bf(vv[c]);
      }
    }
    __syncthreads();
    const uint4* src = (const uint4*)img;
    uint4* dst = (uint4*)((char*)Dt + (size_t)ktile * 32768);
    for (int i = tid; i < 2048; i += 256) dst[i] = src[i];
  }
}

// ================= prep2: gmat_mfma + film_reduce (fused, 256 thr) ================
__global__ __launch_bounds__(256) void prep2_kernel(
    const unsigned short* __restrict__ Wqh, const unsigned short* __restrict__ Wql,
    const unsigned short* __restrict__ Wkh, const unsigned short* __restrict__ Wkl,
    unsigned short* __restrict__ Gt,
    const float* __restrict__ part, const float* __restrict__ bc,
    float* __restrict__ gb)
{
  const int bid = blockIdx.x;
  const int tid = threadIdx.x;

  if (bid < 256) {
    // ---- G = (Wq @ Wk^T)*scale via split MFMA -> hi/lo T64 tiles ----
    const int lane = tid & 63, l15 = lane & 15, g = lane >> 4;
    const int wave = tid >> 6;
    const int t  = (bid << 2) | wave;   // 0..1023
    const int ti = t >> 5, tj = t & 31;
    const int ib = ti << 4, jb = tj << 4;
    const size_t arow = (size_t)(ib + l15) * 512 + (g << 3);
    const size_t brow = (size_t)(jb + l15) * 512 + (g << 3);

    v4f acc = (v4f){0.f, 0.f, 0.f, 0.f};
    #pragma unroll 4
    for (int kk = 0; kk < 16; ++kk) {
      const int kd = kk * 32;
      const v8s ah = *(const v8s*)&Wqh[arow + kd];
      const v8s al = *(const v8s*)&Wql[arow + kd];
      const v8s bh = *(const v8s*)&Wkh[brow + kd];
      const v8s bl = *(const v8s*)&Wkl[brow + kd];
      acc = __builtin_amdgcn_mfma_f32_16x16x32_bf16(ah, bh, acc, 0, 0, 0);
      acc = __builtin_amdgcn_mfma_f32_16x16x32_bf16(al, bh, acc, 0, 0, 0);
      acc = __builtin_amdgcn_mfma_f32_16x16x32_bf16(ah, bl, acc, 0, 0, 0);
    }
    #pragma unroll
    for (int k = 0; k < 4; ++k) {
      const int gi = ib + (g << 2) + k;
      const int gj = jb + l15;
      const float v = acc[k] * SCORE_SCALE;
      const unsigned short hi = f2bf(v);
      const unsigned short lo = f2bf(v - bf2f(hi));
      const int toff = t64_off(gj & 63, gi & 31);
      *(unsigned short*)((char*)Gt + ((size_t)((gi >> 5) * 8 + (gj >> 6)) << 12) + toff) = hi;
      *(unsigned short*)((char*)Gt + ((size_t)(((gi >> 5) + 16) * 8 + (gj >> 6)) << 12) + toff) = lo;
    }
  } else {
    // ---- film_reduce: b(8) x jq(4) ----
    const int rb = bid - 256;   // 0..31
    const int b = rb >> 2, jq = rb & 3;
    const int j = jq * 256 + tid;
    float acc = bc[j];
    #pragma unroll
    for (int sl = 0; sl < 8; ++sl) acc += part[(b * 8 + sl) * 1024 + j];
    gb[b * 1024 + j] = acc;
  }
}

// ---------------- qg projection: QGt = split(FiLM(query)@G + u) ----------
// BK=32, 2-phase prefetch: issue tile k+1 loads, compute tile k, one barrier/iter.
__global__ __launch_bounds__(256) void proj_split(
    const float* __restrict__ A, const unsigned short* __restrict__ Bt,
    const float* __restrict__ bias, const float* __restrict__ gb,
    unsigned short* __restrict__ Qgt)
{
  __shared__ char smem[49152];   // 2 x { LAh 4K | LAl 4K | LBh 8K | LBl 8K }
  const int tid  = threadIdx.x;
  const int lane = tid & 63, l15 = lane & 15, g = lane >> 4;
  const int wave = tid >> 6, wm = wave >> 1, wn = wave & 1;
  const int bid = blockIdx.x;
  const int xcd = bid & 7, idx = bid >> 3;
  const int mBlk = (idx & 15) | (xcd << 4);   // 0..127
  const int nBlk = idx >> 4;                  // 0..3

  const int sr = tid >> 2;   // 0..63
  const int sq = tid & 3;    // k-octet
  const size_t arow = (size_t)(mBlk * 64 + sr) * 512 + sq * 8;
  const int gbbase = ((mBlk >> 4) * 1024) + sq * 8;
  const int awoff = t64_off(sr, sq * 8);

  int aoff[2], boff[4];
  #pragma unroll
  for (int fm = 0; fm < 2; ++fm) aoff[fm] = frag_off(wm * 32 + fm * 16 + l15, g);
  #pragma unroll
  for (int fn = 0; fn < 4; ++fn) {
    const int n = wn * 64 + fn * 16 + l15;   // 0..127
    boff[fn] = ((n >> 6) << 12) + frag_off(n & 63, g);
  }

  v4f acc[2][4];
  #pragma unroll
  for (int fm = 0; fm < 2; ++fm)
    #pragma unroll
    for (int fn = 0; fn < 4; ++fn) acc[fm][fn] = (v4f){0.f, 0.f, 0.f, 0.f};

  auto stageB = [&](int buf, int tk) {
    const char* gsh = (const char*)Bt + ((size_t)(tk * 8 + nBlk * 2) << 12) + (size_t)tid * 16;
    const char* gsl = (const char*)Bt + ((size_t)((tk + 16) * 8 + nBlk * 2) << 12) + (size_t)tid * 16;
    char* dh = smem + buf * 24576 + 8192 + (wave << 10);
    char* dl = smem + buf * 24576 + 16384 + (wave << 10);
    #pragma unroll
    for (int i = 0; i < 2; ++i) {
      gload_lds16(gsh + i * 4096, dh + i * 4096);
      gload_lds16(gsl + i * 4096, dl + i * 4096);
    }
  };
  auto loadA = [&](int tk, float4* r) {
    const int kd = tk * 32;
    r[0] = *(const float4*)&A[arow + kd];
    r[1] = *(const float4*)&A[arow + kd + 4];
    r[2] = *(const float4*)&gb[gbbase + kd];
    r[3] = *(const float4*)&gb[gbbase + kd + 4];
    r[4] = *(const float4*)&gb[gbbase + 512 + kd];
    r[5] = *(const float4*)&gb[gbbase + 512 + kd + 4];
  };
  auto writeA = [&](int buf, float4* r) {
    float4 x0 = r[0], x1 = r[1];
    x0.x = fmaf(x0.x, 1.f + r[2].x, r[4].x); x0.y = fmaf(x0.y, 1.f + r[2].y, r[4].y);
    x0.z = fmaf(x0.z, 1.f + r[2].z, r[4].z); x0.w = fmaf(x0.w, 1.f + r[2].w, r[4].w);
    x1.x = fmaf(x1.x, 1.f + r[3].x, r[5].x); x1.y = fmaf(x1.y, 1.f + r[3].y, r[5].y);
    x1.z = fmaf(x1.z, 1.f + r[3].z, r[5].z); x1.w = fmaf(x1.w, 1.f + r[3].w, r[5].w);
    uint4 hi4, lo4;
    cvt8pair(x0, x1, hi4, lo4);
    *(uint4*)(smem + buf * 24576 + awoff) = hi4;
    *(uint4*)(smem + buf * 24576 + 4096 + awoff) = lo4;
  };

  // prologue: fully stage tile 0 into buf 0
  float4 pr[6];
  stageB(0, 0);
  loadA(0, pr);
  writeA(0, pr);
  __syncthreads();   // drains vmcnt + lgkmcnt

  for (int tk = 0; tk < 16; ++tk) {
    const int cur = tk & 1;
    if (tk < 15) {               // issue next tile's loads (overlap with MFMA)
      stageB(cur ^ 1, tk + 1);
      loadA(tk + 1, pr);
    }
    const char* base = smem + cur * 24576;
    const v8s ah0 = *(const v8s*)(base + aoff[0]);
    const v8s ah1 = *(const v8s*)(base + aoff[1]);
    const v8s al0 = *(const v8s*)(base + 4096 + aoff[0]);
    const v8s al1 = *(const v8s*)(base + 4096 + aoff[1]);
    #pragma unroll
    for (int fn = 0; fn < 4; ++fn) {
      const v8s bh = *(const v8s*)(base + 8192 + boff[fn]);
      const v8s bl = *(const v8s*)(base + 16384 + boff[fn]);
      acc[0][fn] = __builtin_amdgcn_mfma_f32_16x16x32_bf16(ah0, bh, acc[0][fn], 0, 0, 0);
      acc[1][fn] = __builtin_amdgcn_mfma_f32_16x16x32_bf16(ah1, bh, acc[1][fn], 0, 0, 0);
      acc[0][fn] = __builtin_amdgcn_mfma_f32_16x16x32_bf16(al0, bh, acc[0][fn], 0, 0, 0);
      acc[1][fn] = __builtin_amdgcn_mfma_f32_16x16x32_bf16(al1, bh, acc[1][fn], 0, 0, 0);
      acc[0][fn] = __builtin_amdgcn_mfma_f32_16x16x32_bf16(ah0, bl, acc[0][fn], 0, 0, 0);
      acc[1][fn] = __builtin_amdgcn_mfma_f32_16x16x32_bf16(ah1, bl, acc[1][fn], 0, 0, 0);
    }
    if (tk < 15) writeA(cur ^ 1, pr);   // ds_write after MFMA (T14 split)
    __syncthreads();   // one barrier/iter: next tile ready, this buffer read-closed
  }

  // Epilogue: qg value -> bf16 hi/lo, stored as T64 tiles.
  #pragma unroll
  for (int fn = 0; fn < 4; ++fn) {
    const int col = nBlk * 128 + wn * 64 + fn * 16 + l15;   // scores k-dim 0..511
    const float bv = bias[col];
    const int kt = col >> 5;
    const int kk = col & 31;
    #pragma unroll
    for (int fm = 0; fm < 2; ++fm) {
      const int r0 = wm * 32 + fm * 16 + g * 4;
      #pragma unroll
      for (int k = 0; k < 4; ++k) {
        const float vv = acc[fm][fn][k] + bv;
        const unsigned short hi = f2bf(vv);
        const unsigned short lo = f2bf(vv - bf2f(hi));
        const int toff = t64_off(r0 + k, kk);
        *(unsigned short*)((char*)Qgt + ((size_t)(kt * 128 + mBlk) << 12) + toff) = hi;
        *(unsigned short*)((char*)Qgt + ((size_t)((kt + 16) * 128 + mBlk) << 12) + toff) = lo;
      }
    }
  }
}

// ---------------- V projection: BM=64, BN=512, 512 thr, 3-stage counted-vmcnt ------
// Tile t lives in buf t%3. Iter tk: issue loads for t=tk+2; compute t=tk;
// counted vmcnt(5) keeps this iteration's 5 loads in flight across the barrier.
__global__ __launch_bounds__(512) void proj_v(
    const float* __restrict__ A, const unsigned short* __restrict__ Bt,
    const float* __restrict__ bias, unsigned short* __restrict__ Cb)
{
  __shared__ char smem[110592];   // 3 x { LA 4K | LB 32K }
  const int tid  = threadIdx.x;
  const int lane = tid & 63, l15 = lane & 15, g = lane >> 4;
  const int wave = tid >> 6, wm = wave >> 2, wn = wave & 3;
  const int mBlk = blockIdx.x;

  const int sr  = tid >> 3;   // 0..63
  const int sq4 = tid & 7;    // k-quad
  const size_t arow = (size_t)(mBlk * 64 + sr) * 512 + sq4 * 4;
  const int awoff = t64_off(sr, sq4 * 4);

  int aoff[2], boff[8];
  #pragma unroll
  for (int fm = 0; fm < 2; ++fm) aoff[fm] = frag_off(wm * 32 + fm * 16 + l15, g);
  #pragma unroll
  for (int fn = 0; fn < 8; ++fn) {
    const int n = wn * 128 + fn * 16 + l15;
    boff[fn] = ((n >> 6) << 12) + frag_off(n & 63, g);
  }

  v4f acc[2][8];
  #pragma unroll
  for (int fm = 0; fm < 2; ++fm)
    #pragma unroll
    for (int fn = 0; fn < 8; ++fn) acc[fm][fn] = (v4f){0.f, 0.f, 0.f, 0.f};

  auto LAp = [&](int buf) { return smem + buf * 36864; };
  auto LBp = [&](int buf) { return smem + buf * 36864 + 4096; };
  auto stageB = [&](int buf, int tk) {
    const char* gs = (const char*)Bt + ((size_t)tk << 15) + (wave << 12) + (lane << 4);
    char* ld = LBp(buf) + (wave << 12);
    #pragma unroll
    for (int i = 0; i < 4; ++i) gload_lds16(gs + (i << 10), ld + (i << 10));
  };

  // prologue: tile 0 fully staged (drained); tile 1's loads left in flight.
  float4 a0v = *(const float4*)&A[arow];          // tile 0 (compiler waits)
  stageB(0, 0);
  *(uint2*)(LAp(0) + awoff) = cvt4(a0v);
  stageB(1, 1);
  float4 a_f = *(const float4*)&A[arow + 32];     // tile 1 A (in flight)
  asm volatile("s_waitcnt vmcnt(5)" ::: "memory");   // B(buf0) done; B(buf1)+A1 in flight
  asm volatile("s_waitcnt lgkmcnt(0)" ::: "memory");
  __builtin_amdgcn_s_barrier();

  float4 a_ff = a_f;
  for (int tk = 0; tk < 16; ++tk) {
    const int cur = tk % 3;
    const int nxt = (tk + 1) % 3;
    const int nn  = (tk + 2) % 3;
    if (tk < 14) {
      stageB(nn, tk + 2);
      a_ff = *(const float4*)&A[arow + (size_t)(tk + 2) * 32];
    }
    const char* ba = LAp(cur);
    const char* bb = LBp(cur);
    const v8s va0 = *(const v8s*)(ba + aoff[0]);
    const v8s va1 = *(const v8s*)(ba + aoff[1]);
    #pragma unroll
    for (int fn = 0; fn < 8; ++fn) {
      const v8s vb = *(const v8s*)(bb + boff[fn]);
      acc[0][fn] = __builtin_amdgcn_mfma_f32_16x16x32_bf16(va0, vb, acc[0][fn], 0, 0, 0);
      acc[1][fn] = __builtin_amdgcn_mfma_f32_16x16x32_bf16(va1, vb, acc[1][fn], 0, 0, 0);
    }
    if (tk < 15) *(uint2*)(LAp(nxt) + awoff) = cvt4(a_f);  // compiler waits a_f's load
    if (tk < 14) { asm volatile("s_waitcnt vmcnt(5)" ::: "memory"); }
    else         { asm volatile("s_waitcnt vmcnt(0)" ::: "memory"); }
    asm volatile("s_waitcnt lgkmcnt(0)" ::: "memory");
    __builtin_amdgcn_s_barrier();
    a_f = a_ff;
  }

  #pragma unroll
  for (int fn = 0; fn < 8; ++fn) {
    const int col = wn * 128 + fn * 16 + l15;
    const float bv = bias[col];
    #pragma unroll
    for (int fm = 0; fm < 2; ++fm) {
      const int r0 = mBlk * 64 + wm * 32 + fm * 16 + g * 4;
      #pragma unroll
      for (int k = 0; k < 4; ++k)
        Cb[(size_t)(r0 + k) * 512 + col] = f2bf(acc[fm][fn][k] + bv);
    }
  }
}

// ---------------- O projection: BM=64, BN=128, grid 512, 2-phase prefetch -------
__global__ __launch_bounds__(256) void proj_o(
    const float* __restrict__ A, const unsigned short* __restrict__ Bt,
    const float* __restrict__ bias, float* __restrict__ Cf)
{
  __shared__ char smem[24576];   // 2 x { LA 4K | LB 8K }
  const int tid  = threadIdx.x;
  const int lane = tid & 63, l15 = lane & 15, g = lane >> 4;
  const int wave = tid >> 6, wm = wave >> 1, wn = wave & 1;
  const int bid = blockIdx.x;
  const int xcd = bid & 7, idx = bid >> 3;
  const int mBlk = (idx & 15) | (xcd << 4);   // 0..127
  const int nBlk = idx >> 4;                  // 0..3

  const int sr = tid >> 2;   // 0..63
  const int sq = tid & 3;    // k-octet
  const size_t arow = (size_t)(mBlk * 64 + sr) * 512 + sq * 8;
  const int awoff = t64_off(sr, sq * 8);

  int aoff[2], boff[4];
  #pragma unroll
  for (int fm = 0; fm < 2; ++fm) aoff[fm] = frag_off(wm * 32 + fm * 16 + l15, g);
  #pragma unroll
  for (int fn = 0; fn < 4; ++fn) {
    const int n = wn * 64 + fn * 16 + l15;
    boff[fn] = ((n >> 6) << 12) + frag_off(n & 63, g);
  }

  v4f acc[2][4];
  #pragma unroll
  for (int fm = 0; fm < 2; ++fm)
    #pragma unroll
    for (int fn = 0; fn < 4; ++fn) acc[fm][fn] = (v4f){0.f, 0.f, 0.f, 0.f};

  auto stageB = [&](int buf, int tk) {
    const char* gs = (const char*)Bt + ((size_t)tk << 15) + ((size_t)nBlk << 13) + (size_t)tid * 16;
    char* ld = smem + buf * 12288 + 4096 + (wave << 10);
    #pragma unroll
    for (int i = 0; i < 2; ++i)
      gload_lds16(gs + i * 4096, ld + i * 4096);
  };

  // prologue
  float4 x0 = *(const float4*)&A[arow];
  float4 x1 = *(const float4*)&A[arow + 4];
  stageB(0, 0);
  *(uint4*)(smem + awoff) = cvt8hi(x0, x1);
  __syncthreads();

  for (int tk = 0; tk < 16; ++tk) {
    const int cur = tk & 1;
    if (tk < 15) {
      stageB(cur ^ 1, tk + 1);
      x0 = *(const float4*)&A[arow + (tk + 1) * 32];
      x1 = *(const float4*)&A[arow + (tk + 1) * 32 + 4];
    }
    const char* base = smem + cur * 12288;
    const v8s a0 = *(const v8s*)(base + aoff[0]);
    const v8s a1 = *(const v8s*)(base + aoff[1]);
    #pragma unroll
    for (int fn = 0; fn < 4; ++fn) {
      const v8s bb = *(const v8s*)(base + 4096 + boff[fn]);
      acc[0][fn] = __builtin_amdgcn_mfma_f32_16x16x32_bf16(a0, bb, acc[0][fn], 0, 0, 0);
      acc[1][fn] = __builtin_amdgcn_mfma_f32_16x16x32_bf16(a1, bb, acc[1][fn], 0, 0, 0);
    }
    if (tk < 15) *(uint4*)(smem + (cur ^ 1) * 12288 + awoff) = cvt8hi(x0, x1);
    __syncthreads();
  }

  #pragma unroll
  for (int fn = 0; fn < 4; ++fn) {
    const int col = nBlk * 128 + wn * 64 + fn * 16 + l15;
    const float bv = bias[col];
    #pragma unroll
    for (int fm = 0; fm < 2; ++fm) {
      const int r0 = mBlk * 64 + wm * 32 + fm * 16 + g * 4;
      #pragma unroll
      for (int k = 0; k < 4; ++k)
        Cf[(size_t)(r0 + k) * 512 + col] = acc[fm][fn][k] + bv;
    }
  }
}

// ---------------- Windowed scores: S = qg' . src^T  (split hi/lo, single K-pass) ------
__global__ __launch_bounds__(256) void scores_mfma(
    const unsigned short* __restrict__ Qgt, const float* __restrict__ SRC,
    float* __restrict__ S)
{
  const int bs = blockIdx.y;
  const int s = bs & 15, b = bs >> 4;
  const int c  = CENTERS[s];
  const int lo = (c - 2 > 0) ? c - 2 : 0;
  const int hi = (c + 2 < 63) ? c + 2 : 63;
  if ((int)blockIdx.x > hi - lo) return;

  __shared__ char smem[16384];   // LAh | LAl | LBh | LBl (4K each)
  char* const LAh = smem;
  char* const LAl = smem + 4096;
  char* const LBh = smem + 8192;
  char* const LBl = smem + 12288;

  const int tid = threadIdx.x;
  const int lane = tid & 63, l15 = lane & 15, g = lane >> 4;
  const int wave = tid >> 6, wm = wave >> 1, wn = wave & 1;
  const int kvrow0 = (b << 12) + ((lo + (int)blockIdx.x) << 6);
  const int qbase  = bs << 6;
  const int sr = tid >> 2, sq = tid & 3;
  const size_t krow = (size_t)(kvrow0 + sr) * 512 + sq * 8;
  const int awoff = t64_off(sr, sq * 8);

  int aoff[2], boff[2];
  #pragma unroll
  for (int f = 0; f < 2; ++f) {
    aoff[f] = frag_off(wm * 32 + f * 16 + l15, g);
    boff[f] = frag_off(wn * 32 + f * 16 + l15, g);
  }

  v4f acc[2][2];
  #pragma unroll
  for (int i = 0; i < 2; ++i)
    #pragma unroll
    for (int j = 0; j < 2; ++j) acc[i][j] = (v4f){0.f, 0.f, 0.f, 0.f};

  for (int tk = 0; tk < 16; ++tk) {
    const int kd = tk * 32;
    {  // A: QGt hi/lo tiles (rowTile = bs), identity-copy via global_load_lds
      const char* gah = (const char*)Qgt + ((size_t)(tk * 128 + bs) << 12) + (size_t)tid * 16;
      const char* gal = (const char*)Qgt + ((size_t)((tk + 16) * 128 + bs) << 12) + (size_t)tid * 16;
      gload_lds16(gah, LAh + (wave << 10));
      gload_lds16(gal, LAl + (wave << 10));
    }
    {  // B: f32 src -> (hi, lo), swizzled ds_write
      float4 y0 = *(const float4*)&SRC[krow + kd];
      float4 y1 = *(const float4*)&SRC[krow + kd + 4];
      uint4 bhi, blo;
      cvt8pair(y0, y1, bhi, blo);
      *(uint4*)(LBh + awoff) = bhi;
      *(uint4*)(LBl + awoff) = blo;
    }
    __syncthreads();   // write-epoch -> read-epoch
    const v8s a0h = *(const v8s*)(LAh + aoff[0]);
    const v8s a1h = *(const v8s*)(LAh + aoff[1]);
    const v8s a0l = *(const v8s*)(LAl + aoff[0]);
    const v8s a1l = *(const v8s*)(LAl + aoff[1]);
    const v8s b0h = *(const v8s*)(LBh + boff[0]);
    const v8s b1h = *(const v8s*)(LBh + boff[1]);
    const v8s b0l = *(const v8s*)(LBl + boff[0]);
    const v8s b1l = *(const v8s*)(LBl + boff[1]);
    acc[0][0] = __builtin_amdgcn_mfma_f32_16x16x32_bf16(a0h, b0h, acc[0][0], 0, 0, 0);
    acc[0][1] = __builtin_amdgcn_mfma_f32_16x16x32_bf16(a0h, b1h, acc[0][1], 0, 0, 0);
    acc[1][0] = __builtin_amdgcn_mfma_f32_16x16x32_bf16(a1h, b0h, acc[1][0], 0, 0, 0);
    acc[1][1] = __builtin_amdgcn_mfma_f32_16x16x32_bf16(a1h, b1h, acc[1][1], 0, 0, 0);
    acc[0][0] = __builtin_amdgcn_mfma_f32_16x16x32_bf16(a0l, b0h, acc[0][0], 0, 0, 0);
    acc[0][1] = __builtin_amdgcn_mfma_f32_16x16x32_bf16(a0l, b1h, acc[0][1], 0, 0, 0);
    acc[1][0] = __builtin_amdgcn_mfma_f32_16x16x32_bf16(a1l, b0h, acc[1][0], 0, 0, 0);
    acc[1][1] = __builtin_amdgcn_mfma_f32_16x16x32_bf16(a1l, b1h, acc[1][1], 0, 0, 0);
    acc[0][0] = __builtin_amdgcn_mfma_f32_16x16x32_bf16(a0h, b0l, acc[0][0], 0, 0, 0);
    acc[0][1] = __builtin_amdgcn_mfma_f32_16x16x32_bf16(a0h, b1l, acc[0][1], 0, 0, 0);
    acc[1][0] = __builtin_amdgcn_mfma_f32_16x16x32_bf16(a1h, b0l, acc[1][0], 0, 0, 0);
    acc[1][1] = __builtin_amdgcn_mfma_f32_16x16x32_bf16(a1h, b1l, acc[1][1], 0, 0, 0);
    __syncthreads();   // read-epoch -> next write-epoch
  }

  #pragma unroll
  for (int fn = 0; fn < 2; ++fn) {
    const int cl = wn * 32 + fn * 16 + l15;
    const int colS = ((int)blockIdx.x << 6) + cl;
    #pragma unroll
    for (int fm = 0; fm < 2; ++fm) {
      const int r0 = qbase + wm * 32 + fm * 16 + g * 4;
      #pragma unroll
      for (int k = 0; k < 4; ++k)
        S[(size_t)(r0 + k) * NWIN + colS] = acc[fm][fn][k];
    }
  }
}

// ---------------- Top-32 + softmax + V gather: radix-select, batched gather ------
__global__ __launch_bounds__(256) void topk_pv(
    const float* __restrict__ S, const unsigned short* __restrict__ Vb,
    float* __restrict__ O)
{
  __shared__ int   sel_i[4][32];
  __shared__ float sel_p[4][32];

  const int lane = threadIdx.x & 63;
  const int wv   = threadIdx.x >> 6;
  // XCD-affine bijective remap: the 16 blocks of one step-group share b0&7 -> same XCD
  const int b0   = blockIdx.x;
  const int grp  = (b0 & 7) + ((b0 >> 7) << 3);    // 0..127
  const int blk  = (b0 >> 3) & 15;                 // 0..15
  const int row  = (((grp << 4) + blk) << 2) + wv; // 0..8191
  const int b    = row >> 10;
  const int s    = (row >> 6) & 15;
  const int c    = CENTERS[s];
  const int lo   = (c - 2 > 0) ? c - 2 : 0;
  const int hi   = (c + 2 < 63) ? c + 2 : 63;
  const int L    = (hi - lo + 1) << 6;
  const size_t vbase = ((size_t)b << 12) + ((size_t)lo << 6);

  const float* srow = S + (size_t)row * NWIN;
  float f[5]; unsigned uo[5];
  #pragma unroll
  for (int j = 0; j < 5; ++j) {
    const int idx = lane + (j << 6);
    const float v = (idx < L) ? srow[idx] : -__builtin_inff();
    f[j] = v;
    const unsigned fb = __float_as_uint(v);
    uo[j] = (fb & 0x80000000u) ? ~fb : (fb | 0x80000000u);  // order-preserving map
  }

  // row max (softmax shift)
  float m = f[0];
  #pragma unroll
  for (int j = 1; j < 5; ++j) m = fmaxf(m, f[j]);
  #pragma unroll
  for (int off = 32; off > 0; off >>= 1) m = fmaxf(m, __shfl_xor(m, off, 64));

  // T = exact 32nd-largest u (greedy MSB radix select; count via ballot+popc)
  unsigned T = 0u;
  for (int bit = 31; bit >= 0; --bit) {
    const unsigned cand = T | (1u << bit);
    int cnt = 0;
    #pragma unroll
    for (int j = 0; j < 5; ++j)
      cnt += __popcll(__ballot(uo[j] >= cand));
    if (cnt >= 32) T = cand;
  }

  // compaction: strict-greater first, then ==T by ascending index (matches lax.top_k)
  int base = 0;
  #pragma unroll
  for (int j = 0; j < 5; ++j) {
    const unsigned long long gm = __ballot(uo[j] > T);
    if (uo[j] > T) {
      const int rank = base + __builtin_amdgcn_mbcnt_hi(
          (unsigned)(gm >> 32), __builtin_amdgcn_mbcnt_lo((unsigned)gm, 0));
      sel_i[wv][rank] = lane + (j << 6);
      sel_p[wv][rank] = __expf(f[j] - m);
    }
    base += __popcll(gm);
  }
  #pragma unroll
  for (int j = 0; j < 5; ++j) {
    const unsigned long long em = __ballot(uo[j] == T);
    if (uo[j] == T) {
      const int er = base + __builtin_amdgcn_mbcnt_hi(
          (unsigned)(em >> 32), __builtin_amdgcn_mbcnt_lo((unsigned)em, 0));
      if (er < 32) {
        sel_i[wv][er] = lane + (j << 6);
        sel_p[wv][er] = __expf(f[j] - m);
      }
    }
    base += __popcll(em);
  }

  // same-wave LDS visibility (lockstep wave; no block barrier needed)
  asm volatile("s_waitcnt lgkmcnt(0)" ::: "memory");

  const int   si = sel_i[wv][lane & 31];
  const float sp = sel_p[wv][lane & 31];
  float dp = (lane < 32) ? sp : 0.f;
  #pragma unroll
  for (int off = 32; off > 0; off >>= 1) dp += __shfl_xor(dp, off, 64);

  // gather: batch 4 t's -> 16 independent loads in flight, then 32 fmas.
  float oacc[8] = {0.f,0.f,0.f,0.f,0.f,0.f,0.f,0.f};
  #pragma unroll
  for (int tb = 0; tb < 32; tb += 4) {
    unsigned raws[4][4];
    #pragma unroll
    for (int q = 0; q < 4; ++q) {
      const int idx_t = __builtin_amdgcn_readlane(si, tb + q);
      const unsigned short* vrow = Vb + ((vbase + (size_t)idx_t) << 9);
      #pragma unroll
      for (int e = 0; e < 4; ++e)
        raws[q][e] = *(const unsigned*)&vrow[(lane << 1) + (e << 7)];
    }
    #pragma unroll
    for (int q = 0; q < 4; ++q) {
      const float p_t = __uint_as_float(
          (unsigned)__builtin_amdgcn_readlane((int)__float_as_uint(sp), tb + q));
      #pragma unroll
      for (int e = 0; e < 4; ++e) {
        oacc[2*e]     = fmaf(p_t, bflo(raws[q][e]), oacc[2*e]);
        oacc[2*e + 1] = fmaf(p_t, bfhi(raws[q][e]), oacc[2*e + 1]);
      }
    }
  }

  const float inv = 1.0f / dp;
  float* orow = O + ((size_t)row << 9);
  #pragma unroll
  for (int e = 0; e < 4; ++e) {
    float2 o2 = make_float2(oacc[2*e] * inv, oacc[2*e + 1] * inv);
    *(float2*)&orow[(lane << 1) + (e << 7)] = o2;
  }
}

// ---------------------------------------------------------------------------------
extern "C" void kernel_launch(void* const* d_in, const int* in_sizes, int n_in,
                              void* d_out, int out_size, void* d_ws, size_t ws_size,
                              hipStream_t stream)
{
  (void)in_sizes; (void)n_in; (void)out_size; (void)ws_size;

  const float* query  = (const float*)d_in[0];
  const float* source = (const float*)d_in[1];
  const float* ctx1   = (const float*)d_in[2];
  const float* ctx2   = (const float*)d_in[3];
  const float* Wq     = (const float*)d_in[4];
  const float* bq     = (const float*)d_in[5];
  const float* Wk     = (const float*)d_in[6];
  // bk (d_in[7]) only contributes row-constant score terms -> provably droppable
  const float* Wv     = (const float*)d_in[8];
  const float* bv     = (const float*)d_in[9];
  const float* Wo     = (const float*)d_in[10];
  const float* bo     = (const float*)d_in[11];
  const float* Wc     = (const float*)d_in[12];
  const float* bc     = (const float*)d_in[13];
  float* out = (float*)d_out;

  // Workspace (~82.1 MB; round 1 proved >= 94.4 MB available):
  char* ws = (char*)d_ws;
  unsigned short* Qgt  = (unsigned short*)(ws);              // 16,777,216 (32 planes x 128 tiles x 4KB)
  unsigned short* v    = (unsigned short*)(ws + 16777216);   // 33,554,432
  float*          S    = (float*)(ws + 50331648);            // 10,485,760
  float*          ctx  = (float*)(ws + 60817408);            // 16,777,216
  unsigned short* Gt   = (unsigned short*)(ws + 77594624);   //  1,048,576
  unsigned short* Wvt  = (unsigned short*)(ws + 78643200);   //    524,288
  unsigned short* Wot  = (unsigned short*)(ws + 79167488);   //    524,288
  float*          gb   = (float*)(ws + 79691776);            //     32,768
  float*          part = (float*)(ws + 79724544);            //    262,144
  float*          u    = (float*)(ws + 79986688);            //      2,048
  unsigned short* Wqh  = (unsigned short*)(ws + 79988736);   //    524,288
  unsigned short* Wql  = (unsigned short*)(ws + 80513024);   //    524,288
  unsigned short* Wkh  = (unsigned short*)(ws + 81037312);   //    524,288
  unsigned short* Wkl  = (unsigned short*)(ws + 81561600);   //    524,288

  // prep1: film_part(256) | u(128) | wsplit(256) | wconv(32) = 672 blocks
  prep1_kernel<<<672, 256, 0, stream>>>(ctx1, ctx2, Wc, part, Wk, bq, u, Wq,
                                        Wqh, Wql, Wkh, Wkl, Wv, Wo, Wvt, Wot);
  // prep2: gmat(256) | film_reduce(32) = 288 blocks
  prep2_kernel<<<288, 256, 0, stream>>>(Wqh, Wql, Wkh, Wkl, Gt, part, bc, gb);
  // QGt = split(FiLM(query) @ G_scaled + u_scaled)  (2-phase prefetch, 512 blocks)
  proj_split<<<512, 256, 0, stream>>>(query, Gt, u, gb, Qgt);
  // v = source @ Wv + bv   (3-stage counted-vmcnt pipeline, BM=64/BN=512)
  proj_v<<<512, 512, 0, stream>>>(source, Wvt, bv, v);
  // windowed scores: A via gload from QGt (no cvt), B cvt'd from f32 source
  scores_mfma<<<dim3(5, 128), 256, 0, stream>>>(Qgt, source, S);
  // top-32 + softmax + PV  (radix-select, batched gather)
  topk_pv<<<2048, 256, 0, stream>>>(S, v, ctx);
  // out = ctx @ Wo + bo   (2-phase prefetch, 64x128 tile, 512 blocks)
  proj_o<<<512, 256, 0, stream>>>(ctx, Wot, bo, out);
}

// Round 19
// 142.525 us; speedup vs baseline: 1.0446x; 1.0446x over previous
//
#include <hip/hip_runtime.h>

// LocalTopKCrossReadout: B=8, Lq=1024 (16 steps x 64), Lkv=4096 (64 x 64),
// DIM=512, WINDOW=2 (<=5 steps = 320 cols), TOPK=32.
#define NWIN 320
#define SCORE_SCALE 0.04419417382415922f  // 1/sqrt(512)

__constant__ int CENTERS[16] = {0,4,8,13,17,21,25,29,34,38,42,46,50,55,59,63};

typedef __attribute__((ext_vector_type(8))) short v8s;   // 8 bf16
typedef __attribute__((ext_vector_type(4))) float v4f;   // 4 f32 acc

__device__ __forceinline__ float bflo(unsigned u) { return __uint_as_float(u << 16); }
__device__ __forceinline__ float bfhi(unsigned u) { return __uint_as_float(u & 0xffff0000u); }
__device__ __forceinline__ float bf2f(unsigned short h) { return __uint_as_float(((unsigned)h) << 16); }
__device__ __forceinline__ unsigned short f2bf(float x) {
  unsigned u = __float_as_uint(x);
  unsigned r = 0x7fffu + ((u >> 16) & 1u);   // RNE
  return (unsigned short)((u + r) >> 16);
}

// ---- T64 tile: 64 rows x 32 k bf16 in 4096 B, XOR-swizzled for conflict-free b128 ----
__device__ __forceinline__ int t64_off(int r, int k) {
  return ((r & 31) << 7) + (((((r >> 5) << 2) | (k >> 3)) ^ (r & 7)) << 4) + ((k & 7) << 1);
}
__device__ __forceinline__ int frag_off(int r, int g) {
  return ((r & 31) << 7) + (((((r >> 5) << 2) | g) ^ (r & 7)) << 4);
}

__device__ __forceinline__ void gload_lds16(const void* g, void* l) {
  __builtin_amdgcn_global_load_lds((const __attribute__((address_space(1))) unsigned int*)g,
                                   (__attribute__((address_space(3))) unsigned int*)l, 16, 0, 0);
}

// pack 8 f32 -> hi-bf16 plane AND lo-residual plane in one shot
__device__ __forceinline__ void cvt8pair(float4 a, float4 b, uint4& hi4, uint4& lo4) {
  float v[8] = {a.x, a.y, a.z, a.w, b.x, b.y, b.z, b.w};
  unsigned short h[8], l[8];
  #pragma unroll
  for (int e = 0; e < 8; ++e) {
    h[e] = f2bf(v[e]);
    l[e] = f2bf(v[e] - bf2f(h[e]));
  }
  hi4.x = (unsigned)h[0] | ((unsigned)h[1] << 16);
  hi4.y = (unsigned)h[2] | ((unsigned)h[3] << 16);
  hi4.z = (unsigned)h[4] | ((unsigned)h[5] << 16);
  hi4.w = (unsigned)h[6] | ((unsigned)h[7] << 16);
  lo4.x = (unsigned)l[0] | ((unsigned)l[1] << 16);
  lo4.y = (unsigned)l[2] | ((unsigned)l[3] << 16);
  lo4.z = (unsigned)l[4] | ((unsigned)l[5] << 16);
  lo4.w = (unsigned)l[6] | ((unsigned)l[7] << 16);
}

__device__ __forceinline__ uint4 cvt8hi(float4 a, float4 b) {
  uint4 r;
  r.x = (unsigned)f2bf(a.x) | ((unsigned)f2bf(a.y) << 16);
  r.y = (unsigned)f2bf(a.z) | ((unsigned)f2bf(a.w) << 16);
  r.z = (unsigned)f2bf(b.x) | ((unsigned)f2bf(b.y) << 16);
  r.w = (unsigned)f2bf(b.z) | ((unsigned)f2bf(b.w) << 16);
  return r;
}

__device__ __forceinline__ uint2 cvt4(float4 a) {
  uint2 r;
  r.x = (unsigned)f2bf(a.x) | ((unsigned)f2bf(a.y) << 16);
  r.y = (unsigned)f2bf(a.z) | ((unsigned)f2bf(a.w) << 16);
  return r;
}

// ================= prep1: film_part + u + wsplit + wconv (fused, 256 thr) =========
__global__ __launch_bounds__(256) void prep1_kernel(
    const float* __restrict__ ctx1, const float* __restrict__ ctx2,
    const float* __restrict__ Wc,  float* __restrict__ part,
    const float* __restrict__ Wk,  const float* __restrict__ bq, float* __restrict__ u,
    const float* __restrict__ Wq,
    unsigned short* __restrict__ Wqh, unsigned short* __restrict__ Wql,
    unsigned short* __restrict__ Wkh, unsigned short* __restrict__ Wkl,
    const float* __restrict__ Wv, const float* __restrict__ Wo,
    unsigned short* __restrict__ Wvt, unsigned short* __restrict__ Wot)
{
  __shared__ char img[32768];
  const int bid = blockIdx.x;
  const int tid = threadIdx.x;

  if (bid < 256) {
    // ---- film_part: b(8) x sl(8) x jq(4) ----
    const int b = bid >> 5, sl = (bid >> 2) & 7, jq = bid & 3;
    const int j = jq * 256 + tid;
    const int i0 = sl * 128;
    float acc = 0.f;
    #pragma unroll 4
    for (int t = 0; t < 128; ++t) {
      const int i = i0 + t;
      const float f = (i < 512) ? ctx1[b * 512 + i] : ctx2[b * 512 + i - 512];
      acc = fmaf(f, Wc[(size_t)i * 1024 + j], acc);
    }
    part[(b * 8 + sl) * 1024 + j] = acc;
  } else if (bid < 384) {
    // ---- u = (Wk . bq) * scale: 4 d per block (one per wave) ----
    const int d = (bid - 256) * 4 + (tid >> 6);
    const int lane = tid & 63;
    float4 a0 = *(const float4*)&Wk[(size_t)d * 512 + lane * 8];
    float4 a1 = *(const float4*)&Wk[(size_t)d * 512 + lane * 8 + 4];
    float4 c0 = *(const float4*)&bq[lane * 8];
    float4 c1 = *(const float4*)&bq[lane * 8 + 4];
    float s = a0.x*c0.x + a0.y*c0.y + a0.z*c0.z + a0.w*c0.w
            + a1.x*c1.x + a1.y*c1.y + a1.z*c1.z + a1.w*c1.w;
    #pragma unroll
    for (int off = 32; off > 0; off >>= 1) s += __shfl_xor(s, off, 64);
    if (lane == 0) u[d] = s * SCORE_SCALE;
  } else if (bid < 640) {
    // ---- wsplit: Wq/Wk -> row-major bf16 hi/lo planes ----
    const int b = bid - 384;          // 0..255
    const int mat = b >> 7;
    const float* Wsrc = mat ? Wk : Wq;
    unsigned short* Wh = mat ? Wkh : Wqh;
    unsigned short* Wl = mat ? Wkl : Wql;
    const size_t e0 = (((size_t)(b & 127) * 256) + tid) * 8;
    float4 x0 = *(const float4*)&Wsrc[e0];
    float4 x1 = *(const float4*)&Wsrc[e0 + 4];
    uint4 h4, l4;
    cvt8pair(x0, x1, h4, l4);
    *(uint4*)&Wh[e0] = h4;
    *(uint4*)&Wl[e0] = l4;
  } else {
    // ---- wconv: Wv/Wo -> T64 hi tiles (W^T layout) ----
    const int cb = bid - 640;         // 0..31
    const int ktile = cb & 15;
    const int mat   = cb >> 4;
    const float* W = mat ? Wo : Wv;
    unsigned short* Dt = mat ? Wot : Wvt;
    const int k  = tid >> 3;
    const int nt = tid & 7;
    #pragma unroll
    for (int e4 = 0; e4 < 16; ++e4) {
      float4 w = *(const float4*)&W[(size_t)(ktile * 32 + k) * 512 + nt * 64 + e4 * 4];
      float vv[4] = {w.x, w.y, w.z, w.w};
      #pragma unroll
      for (int c = 0; c < 4; ++c) {
        const int n = e4 * 4 + c;
        *(unsigned short*)(img + nt * 4096 + t64_off(n, k)) = f2bf(vv[c]);
      }
    }
    __syncthreads();
    const uint4* src = (const uint4*)img;
    uint4* dst = (uint4*)((char*)Dt + (size_t)ktile * 32768);
    for (int i = tid; i < 2048; i += 256) dst[i] = src[i];
  }
}

// ================= prep2: gmat_mfma + film_reduce (fused, 256 thr) ================
__global__ __launch_bounds__(256) void prep2_kernel(
    const unsigned short* __restrict__ Wqh, const unsigned short* __restrict__ Wql,
    const unsigned short* __restrict__ Wkh, const unsigned short* __restrict__ Wkl,
    unsigned short* __restrict__ Gt,
    const float* __restrict__ part, const float* __restrict__ bc,
    float* __restrict__ gb)
{
  const int bid = blockIdx.x;
  const int tid = threadIdx.x;

  if (bid < 256) {
    // ---- G = (Wq @ Wk^T)*scale via split MFMA -> hi/lo T64 tiles ----
    const int lane = tid & 63, l15 = lane & 15, g = lane >> 4;
    const int wave = tid >> 6;
    const int t  = (bid << 2) | wave;   // 0..1023
    const int ti = t >> 5, tj = t & 31;
    const int ib = ti << 4, jb = tj << 4;
    const size_t arow = (size_t)(ib + l15) * 512 + (g << 3);
    const size_t brow = (size_t)(jb + l15) * 512 + (g << 3);

    v4f acc = (v4f){0.f, 0.f, 0.f, 0.f};
    #pragma unroll 4
    for (int kk = 0; kk < 16; ++kk) {
      const int kd = kk * 32;
      const v8s ah = *(const v8s*)&Wqh[arow + kd];
      const v8s al = *(const v8s*)&Wql[arow + kd];
      const v8s bh = *(const v8s*)&Wkh[brow + kd];
      const v8s bl = *(const v8s*)&Wkl[brow + kd];
      acc = __builtin_amdgcn_mfma_f32_16x16x32_bf16(ah, bh, acc, 0, 0, 0);
      acc = __builtin_amdgcn_mfma_f32_16x16x32_bf16(al, bh, acc, 0, 0, 0);
      acc = __builtin_amdgcn_mfma_f32_16x16x32_bf16(ah, bl, acc, 0, 0, 0);
    }
    #pragma unroll
    for (int k = 0; k < 4; ++k) {
      const int gi = ib + (g << 2) + k;
      const int gj = jb + l15;
      const float v = acc[k] * SCORE_SCALE;
      const unsigned short hi = f2bf(v);
      const unsigned short lo = f2bf(v - bf2f(hi));
      const int toff = t64_off(gj & 63, gi & 31);
      *(unsigned short*)((char*)Gt + ((size_t)((gi >> 5) * 8 + (gj >> 6)) << 12) + toff) = hi;
      *(unsigned short*)((char*)Gt + ((size_t)(((gi >> 5) + 16) * 8 + (gj >> 6)) << 12) + toff) = lo;
    }
  } else {
    // ---- film_reduce: b(8) x jq(4) ----
    const int rb = bid - 256;   // 0..31
    const int b = rb >> 2, jq = rb & 3;
    const int j = jq * 256 + tid;
    float acc = bc[j];
    #pragma unroll
    for (int sl = 0; sl < 8; ++sl) acc += part[(b * 8 + sl) * 1024 + j];
    gb[b * 1024 + j] = acc;
  }
}

// ---------------- qg projection: QGt = split(FiLM(query)@G + u) ----------
// BK=32, 2-phase prefetch: issue tile k+1 loads, compute tile k, one barrier/iter.
__global__ __launch_bounds__(256) void proj_split(
    const float* __restrict__ A, const unsigned short* __restrict__ Bt,
    const float* __restrict__ bias, const float* __restrict__ gb,
    unsigned short* __restrict__ Qgt)
{
  __shared__ char smem[49152];   // 2 x { LAh 4K | LAl 4K | LBh 8K | LBl 8K }
  const int tid  = threadIdx.x;
  const int lane = tid & 63, l15 = lane & 15, g = lane >> 4;
  const int wave = tid >> 6, wm = wave >> 1, wn = wave & 1;
  const int bid = blockIdx.x;
  const int xcd = bid & 7, idx = bid >> 3;
  const int mBlk = (idx & 15) | (xcd << 4);   // 0..127
  const int nBlk = idx >> 4;                  // 0..3

  const int sr = tid >> 2;   // 0..63
  const int sq = tid & 3;    // k-octet
  const size_t arow = (size_t)(mBlk * 64 + sr) * 512 + sq * 8;
  const int gbbase = ((mBlk >> 4) * 1024) + sq * 8;
  const int awoff = t64_off(sr, sq * 8);

  int aoff[2], boff[4];
  #pragma unroll
  for (int fm = 0; fm < 2; ++fm) aoff[fm] = frag_off(wm * 32 + fm * 16 + l15, g);
  #pragma unroll
  for (int fn = 0; fn < 4; ++fn) {
    const int n = wn * 64 + fn * 16 + l15;   // 0..127
    boff[fn] = ((n >> 6) << 12) + frag_off(n & 63, g);
  }

  v4f acc[2][4];
  #pragma unroll
  for (int fm = 0; fm < 2; ++fm)
    #pragma unroll
    for (int fn = 0; fn < 4; ++fn) acc[fm][fn] = (v4f){0.f, 0.f, 0.f, 0.f};

  auto stageB = [&](int buf, int tk) {
    const char* gsh = (const char*)Bt + ((size_t)(tk * 8 + nBlk * 2) << 12) + (size_t)tid * 16;
    const char* gsl = (const char*)Bt + ((size_t)((tk + 16) * 8 + nBlk * 2) << 12) + (size_t)tid * 16;
    char* dh = smem + buf * 24576 + 8192 + (wave << 10);
    char* dl = smem + buf * 24576 + 16384 + (wave << 10);
    #pragma unroll
    for (int i = 0; i < 2; ++i) {
      gload_lds16(gsh + i * 4096, dh + i * 4096);
      gload_lds16(gsl + i * 4096, dl + i * 4096);
    }
  };
  auto loadA = [&](int tk, float4* r) {
    const int kd = tk * 32;
    r[0] = *(const float4*)&A[arow + kd];
    r[1] = *(const float4*)&A[arow + kd + 4];
    r[2] = *(const float4*)&gb[gbbase + kd];
    r[3] = *(const float4*)&gb[gbbase + kd + 4];
    r[4] = *(const float4*)&gb[gbbase + 512 + kd];
    r[5] = *(const float4*)&gb[gbbase + 512 + kd + 4];
  };
  auto writeA = [&](int buf, float4* r) {
    float4 x0 = r[0], x1 = r[1];
    x0.x = fmaf(x0.x, 1.f + r[2].x, r[4].x); x0.y = fmaf(x0.y, 1.f + r[2].y, r[4].y);
    x0.z = fmaf(x0.z, 1.f + r[2].z, r[4].z); x0.w = fmaf(x0.w, 1.f + r[2].w, r[4].w);
    x1.x = fmaf(x1.x, 1.f + r[3].x, r[5].x); x1.y = fmaf(x1.y, 1.f + r[3].y, r[5].y);
    x1.z = fmaf(x1.z, 1.f + r[3].z, r[5].z); x1.w = fmaf(x1.w, 1.f + r[3].w, r[5].w);
    uint4 hi4, lo4;
    cvt8pair(x0, x1, hi4, lo4);
    *(uint4*)(smem + buf * 24576 + awoff) = hi4;
    *(uint4*)(smem + buf * 24576 + 4096 + awoff) = lo4;
  };

  // prologue: fully stage tile 0 into buf 0
  float4 pr[6];
  stageB(0, 0);
  loadA(0, pr);
  writeA(0, pr);
  __syncthreads();   // drains vmcnt + lgkmcnt

  for (int tk = 0; tk < 16; ++tk) {
    const int cur = tk & 1;
    if (tk < 15) {               // issue next tile's loads (overlap with MFMA)
      stageB(cur ^ 1, tk + 1);
      loadA(tk + 1, pr);
    }
    const char* base = smem + cur * 24576;
    const v8s ah0 = *(const v8s*)(base + aoff[0]);
    const v8s ah1 = *(const v8s*)(base + aoff[1]);
    const v8s al0 = *(const v8s*)(base + 4096 + aoff[0]);
    const v8s al1 = *(const v8s*)(base + 4096 + aoff[1]);
    #pragma unroll
    for (int fn = 0; fn < 4; ++fn) {
      const v8s bh = *(const v8s*)(base + 8192 + boff[fn]);
      const v8s bl = *(const v8s*)(base + 16384 + boff[fn]);
      acc[0][fn] = __builtin_amdgcn_mfma_f32_16x16x32_bf16(ah0, bh, acc[0][fn], 0, 0, 0);
      acc[1][fn] = __builtin_amdgcn_mfma_f32_16x16x32_bf16(ah1, bh, acc[1][fn], 0, 0, 0);
      acc[0][fn] = __builtin_amdgcn_mfma_f32_16x16x32_bf16(al0, bh, acc[0][fn], 0, 0, 0);
      acc[1][fn] = __builtin_amdgcn_mfma_f32_16x16x32_bf16(al1, bh, acc[1][fn], 0, 0, 0);
      acc[0][fn] = __builtin_amdgcn_mfma_f32_16x16x32_bf16(ah0, bl, acc[0][fn], 0, 0, 0);
      acc[1][fn] = __builtin_amdgcn_mfma_f32_16x16x32_bf16(ah1, bl, acc[1][fn], 0, 0, 0);
    }
    if (tk < 15) writeA(cur ^ 1, pr);   // ds_write after MFMA (T14 split)
    __syncthreads();   // one barrier/iter: next tile ready, this buffer read-closed
  }

  // Epilogue: qg value -> bf16 hi/lo, stored as T64 tiles.
  #pragma unroll
  for (int fn = 0; fn < 4; ++fn) {
    const int col = nBlk * 128 + wn * 64 + fn * 16 + l15;   // scores k-dim 0..511
    const float bv = bias[col];
    const int kt = col >> 5;
    const int kk = col & 31;
    #pragma unroll
    for (int fm = 0; fm < 2; ++fm) {
      const int r0 = wm * 32 + fm * 16 + g * 4;
      #pragma unroll
      for (int k = 0; k < 4; ++k) {
        const float vv = acc[fm][fn][k] + bv;
        const unsigned short hi = f2bf(vv);
        const unsigned short lo = f2bf(vv - bf2f(hi));
        const int toff = t64_off(r0 + k, kk);
        *(unsigned short*)((char*)Qgt + ((size_t)(kt * 128 + mBlk) << 12) + toff) = hi;
        *(unsigned short*)((char*)Qgt + ((size_t)((kt + 16) * 128 + mBlk) << 12) + toff) = lo;
      }
    }
  }
}

// ---------------- V projection: BM=64, BN=512, 512 thr, 2-phase prefetch ------
__global__ __launch_bounds__(512) void proj_v(
    const float* __restrict__ A, const unsigned short* __restrict__ Bt,
    const float* __restrict__ bias, unsigned short* __restrict__ Cb)
{
  __shared__ char smem[8192 + 65536];   // LA 2x4K | LB 2x32K
  char* const LA = smem;
  char* const LB = smem + 8192;

  const int tid  = threadIdx.x;
  const int lane = tid & 63, l15 = lane & 15, g = lane >> 4;
  const int wave = tid >> 6, wm = wave >> 2, wn = wave & 3;
  const int mBlk = blockIdx.x;

  const int sr  = tid >> 3;   // 0..63
  const int sq4 = tid & 7;    // k-quad
  const size_t arow = (size_t)(mBlk * 64 + sr) * 512 + sq4 * 4;
  const int awoff = t64_off(sr, sq4 * 4);

  int aoff[2], boff[8];
  #pragma unroll
  for (int fm = 0; fm < 2; ++fm) aoff[fm] = frag_off(wm * 32 + fm * 16 + l15, g);
  #pragma unroll
  for (int fn = 0; fn < 8; ++fn) {
    const int n = wn * 128 + fn * 16 + l15;
    boff[fn] = ((n >> 6) << 12) + frag_off(n & 63, g);
  }

  v4f acc[2][8];
  #pragma unroll
  for (int fm = 0; fm < 2; ++fm)
    #pragma unroll
    for (int fn = 0; fn < 8; ++fn) acc[fm][fn] = (v4f){0.f, 0.f, 0.f, 0.f};

  auto stageB = [&](int buf, int tk) {
    const char* gs = (const char*)Bt + ((size_t)tk << 15) + (wave << 12) + (lane << 4);
    char* ld = LB + (buf << 15) + (wave << 12);
    #pragma unroll
    for (int i = 0; i < 4; ++i) gload_lds16(gs + (i << 10), ld + (i << 10));
  };

  // prologue: fully stage tile 0 into buf 0
  float4 xa = *(const float4*)&A[arow];
  stageB(0, 0);
  *(uint2*)(LA + awoff) = cvt4(xa);
  __syncthreads();

  for (int tk = 0; tk < 16; ++tk) {
    const int cur = tk & 1;
    if (tk < 15) {
      stageB(cur ^ 1, tk + 1);
      xa = *(const float4*)&A[arow + (tk + 1) * 32];
    }
    const v8s a0 = *(const v8s*)(LA + (cur << 12) + aoff[0]);
    const v8s a1 = *(const v8s*)(LA + (cur << 12) + aoff[1]);
    #pragma unroll
    for (int fn = 0; fn < 8; ++fn) {
      const v8s bb = *(const v8s*)(LB + (cur << 15) + boff[fn]);
      acc[0][fn] = __builtin_amdgcn_mfma_f32_16x16x32_bf16(a0, bb, acc[0][fn], 0, 0, 0);
      acc[1][fn] = __builtin_amdgcn_mfma_f32_16x16x32_bf16(a1, bb, acc[1][fn], 0, 0, 0);
    }
    if (tk < 15) *(uint2*)(LA + ((cur ^ 1) << 12) + awoff) = cvt4(xa);
    __syncthreads();
  }

  #pragma unroll
  for (int fn = 0; fn < 8; ++fn) {
    const int col = wn * 128 + fn * 16 + l15;
    const float bv = bias[col];
    #pragma unroll
    for (int fm = 0; fm < 2; ++fm) {
      const int r0 = mBlk * 64 + wm * 32 + fm * 16 + g * 4;
      #pragma unroll
      for (int k = 0; k < 4; ++k)
        Cb[(size_t)(r0 + k) * 512 + col] = f2bf(acc[fm][fn][k] + bv);
    }
  }
}

// ---------------- O projection: BM=64, BN=128, grid 512, 2-phase prefetch -------
__global__ __launch_bounds__(256) void proj_o(
    const float* __restrict__ A, const unsigned short* __restrict__ Bt,
    const float* __restrict__ bias, float* __restrict__ Cf)
{
  __shared__ char smem[24576];   // 2 x { LA 4K | LB 8K }
  const int tid  = threadIdx.x;
  const int lane = tid & 63, l15 = lane & 15, g = lane >> 4;
  const int wave = tid >> 6, wm = wave >> 1, wn = wave & 1;
  const int bid = blockIdx.x;
  const int xcd = bid & 7, idx = bid >> 3;
  const int mBlk = (idx & 15) | (xcd << 4);   // 0..127
  const int nBlk = idx >> 4;                  // 0..3

  const int sr = tid >> 2;   // 0..63
  const int sq = tid & 3;    // k-octet
  const size_t arow = (size_t)(mBlk * 64 + sr) * 512 + sq * 8;
  const int awoff = t64_off(sr, sq * 8);

  int aoff[2], boff[4];
  #pragma unroll
  for (int fm = 0; fm < 2; ++fm) aoff[fm] = frag_off(wm * 32 + fm * 16 + l15, g);
  #pragma unroll
  for (int fn = 0; fn < 4; ++fn) {
    const int n = wn * 64 + fn * 16 + l15;
    boff[fn] = ((n >> 6) << 12) + frag_off(n & 63, g);
  }

  v4f acc[2][4];
  #pragma unroll
  for (int fm = 0; fm < 2; ++fm)
    #pragma unroll
    for (int fn = 0; fn < 4; ++fn) acc[fm][fn] = (v4f){0.f, 0.f, 0.f, 0.f};

  auto stageB = [&](int buf, int tk) {
    const char* gs = (const char*)Bt + ((size_t)tk << 15) + ((size_t)nBlk << 13) + (size_t)tid * 16;
    char* ld = smem + buf * 12288 + 4096 + (wave << 10);
    #pragma unroll
    for (int i = 0; i < 2; ++i)
      gload_lds16(gs + i * 4096, ld + i * 4096);
  };

  // prologue
  float4 x0 = *(const float4*)&A[arow];
  float4 x1 = *(const float4*)&A[arow + 4];
  stageB(0, 0);
  *(uint4*)(smem + awoff) = cvt8hi(x0, x1);
  __syncthreads();

  for (int tk = 0; tk < 16; ++tk) {
    const int cur = tk & 1;
    if (tk < 15) {
      stageB(cur ^ 1, tk + 1);
      x0 = *(const float4*)&A[arow + (tk + 1) * 32];
      x1 = *(const float4*)&A[arow + (tk + 1) * 32 + 4];
    }
    const char* base = smem + cur * 12288;
    const v8s a0 = *(const v8s*)(base + aoff[0]);
    const v8s a1 = *(const v8s*)(base + aoff[1]);
    #pragma unroll
    for (int fn = 0; fn < 4; ++fn) {
      const v8s bb = *(const v8s*)(base + 4096 + boff[fn]);
      acc[0][fn] = __builtin_amdgcn_mfma_f32_16x16x32_bf16(a0, bb, acc[0][fn], 0, 0, 0);
      acc[1][fn] = __builtin_amdgcn_mfma_f32_16x16x32_bf16(a1, bb, acc[1][fn], 0, 0, 0);
    }
    if (tk < 15) *(uint4*)(smem + (cur ^ 1) * 12288 + awoff) = cvt8hi(x0, x1);
    __syncthreads();
  }

  #pragma unroll
  for (int fn = 0; fn < 4; ++fn) {
    const int col = nBlk * 128 + wn * 64 + fn * 16 + l15;
    const float bv = bias[col];
    #pragma unroll
    for (int fm = 0; fm < 2; ++fm) {
      const int r0 = mBlk * 64 + wm * 32 + fm * 16 + g * 4;
      #pragma unroll
      for (int k = 0; k < 4; ++k)
        Cf[(size_t)(r0 + k) * 512 + col] = acc[fm][fn][k] + bv;
    }
  }
}

// ---------------- Windowed scores: S = qg' . src^T  (2-phase prefetch) ------
__global__ __launch_bounds__(256) void scores_mfma(
    const unsigned short* __restrict__ Qgt, const float* __restrict__ SRC,
    float* __restrict__ S)
{
  const int bs = blockIdx.y;
  const int s = bs & 15, b = bs >> 4;
  const int c  = CENTERS[s];
  const int lo = (c - 2 > 0) ? c - 2 : 0;
  const int hi = (c + 2 < 63) ? c + 2 : 63;
  if ((int)blockIdx.x > hi - lo) return;

  __shared__ char smem[32768];   // 2 x { LAh 4K | LAl 4K | LBh 4K | LBl 4K }
  const int tid = threadIdx.x;
  const int lane = tid & 63, l15 = lane & 15, g = lane >> 4;
  const int wave = tid >> 6, wm = wave >> 1, wn = wave & 1;
  const int kvrow0 = (b << 12) + ((lo + (int)blockIdx.x) << 6);
  const int qbase  = bs << 6;
  const int sr = tid >> 2, sq = tid & 3;
  const size_t krow = (size_t)(kvrow0 + sr) * 512 + sq * 8;
  const int awoff = t64_off(sr, sq * 8);

  int aoff[2], boff[2];
  #pragma unroll
  for (int f = 0; f < 2; ++f) {
    aoff[f] = frag_off(wm * 32 + f * 16 + l15, g);
    boff[f] = frag_off(wn * 32 + f * 16 + l15, g);
  }

  v4f acc[2][2];
  #pragma unroll
  for (int i = 0; i < 2; ++i)
    #pragma unroll
    for (int j = 0; j < 2; ++j) acc[i][j] = (v4f){0.f, 0.f, 0.f, 0.f};

  auto stageA = [&](int buf, int tk) {
    const char* gah = (const char*)Qgt + ((size_t)(tk * 128 + bs) << 12) + (size_t)tid * 16;
    const char* gal = (const char*)Qgt + ((size_t)((tk + 16) * 128 + bs) << 12) + (size_t)tid * 16;
    gload_lds16(gah, smem + buf * 16384 + (wave << 10));
    gload_lds16(gal, smem + buf * 16384 + 4096 + (wave << 10));
  };
  auto loadB = [&](int tk, float4* r) {
    const int kd = tk * 32;
    r[0] = *(const float4*)&SRC[krow + kd];
    r[1] = *(const float4*)&SRC[krow + kd + 4];
  };
  auto writeB = [&](int buf, float4* r) {
    uint4 bhi, blo;
    cvt8pair(r[0], r[1], bhi, blo);
    *(uint4*)(smem + buf * 16384 + 8192 + awoff) = bhi;
    *(uint4*)(smem + buf * 16384 + 12288 + awoff) = blo;
  };

  // prologue: fully stage tile 0 into buf 0
  float4 pr[2];
  stageA(0, 0);
  loadB(0, pr);
  writeB(0, pr);
  __syncthreads();

  for (int tk = 0; tk < 16; ++tk) {
    const int cur = tk & 1;
    if (tk < 15) {
      stageA(cur ^ 1, tk + 1);
      loadB(tk + 1, pr);
    }
    const char* base = smem + cur * 16384;
    const v8s a0h = *(const v8s*)(base + aoff[0]);
    const v8s a1h = *(const v8s*)(base + aoff[1]);
    const v8s a0l = *(const v8s*)(base + 4096 + aoff[0]);
    const v8s a1l = *(const v8s*)(base + 4096 + aoff[1]);
    const v8s b0h = *(const v8s*)(base + 8192 + boff[0]);
    const v8s b1h = *(const v8s*)(base + 8192 + boff[1]);
    const v8s b0l = *(const v8s*)(base + 12288 + boff[0]);
    const v8s b1l = *(const v8s*)(base + 12288 + boff[1]);
    acc[0][0] = __builtin_amdgcn_mfma_f32_16x16x32_bf16(a0h, b0h, acc[0][0], 0, 0, 0);
    acc[0][1] = __builtin_amdgcn_mfma_f32_16x16x32_bf16(a0h, b1h, acc[0][1], 0, 0, 0);
    acc[1][0] = __builtin_amdgcn_mfma_f32_16x16x32_bf16(a1h, b0h, acc[1][0], 0, 0, 0);
    acc[1][1] = __builtin_amdgcn_mfma_f32_16x16x32_bf16(a1h, b1h, acc[1][1], 0, 0, 0);
    acc[0][0] = __builtin_amdgcn_mfma_f32_16x16x32_bf16(a0l, b0h, acc[0][0], 0, 0, 0);
    acc[0][1] = __builtin_amdgcn_mfma_f32_16x16x32_bf16(a0l, b1h, acc[0][1], 0, 0, 0);
    acc[1][0] = __builtin_amdgcn_mfma_f32_16x16x32_bf16(a1l, b0h, acc[1][0], 0, 0, 0);
    acc[1][1] = __builtin_amdgcn_mfma_f32_16x16x32_bf16(a1l, b1h, acc[1][1], 0, 0, 0);
    acc[0][0] = __builtin_amdgcn_mfma_f32_16x16x32_bf16(a0h, b0l, acc[0][0], 0, 0, 0);
    acc[0][1] = __builtin_amdgcn_mfma_f32_16x16x32_bf16(a0h, b1l, acc[0][1], 0, 0, 0);
    acc[1][0] = __builtin_amdgcn_mfma_f32_16x16x32_bf16(a1h, b0l, acc[1][0], 0, 0, 0);
    acc[1][1] = __builtin_amdgcn_mfma_f32_16x16x32_bf16(a1h, b1l, acc[1][1], 0, 0, 0);
    if (tk < 15) writeB(cur ^ 1, pr);   // ds_write after MFMA (T14 split)
    __syncthreads();
  }

  #pragma unroll
  for (int fn = 0; fn < 2; ++fn) {
    const int cl = wn * 32 + fn * 16 + l15;
    const int colS = ((int)blockIdx.x << 6) + cl;
    #pragma unroll
    for (int fm = 0; fm < 2; ++fm) {
      const int r0 = qbase + wm * 32 + fm * 16 + g * 4;
      #pragma unroll
      for (int k = 0; k < 4; ++k)
        S[(size_t)(r0 + k) * NWIN + colS] = acc[fm][fn][k];
    }
  }
}

// ---------------- Top-32 + softmax + V gather: radix-select, batched gather ------
__global__ __launch_bounds__(256) void topk_pv(
    const float* __restrict__ S, const unsigned short* __restrict__ Vb,
    float* __restrict__ O)
{
  __shared__ int   sel_i[4][32];
  __shared__ float sel_p[4][32];

  const int lane = threadIdx.x & 63;
  const int wv   = threadIdx.x >> 6;
  // XCD-affine bijective remap: the 16 blocks of one step-group share b0&7 -> same XCD
  const int b0   = blockIdx.x;
  const int grp  = (b0 & 7) + ((b0 >> 7) << 3);    // 0..127
  const int blk  = (b0 >> 3) & 15;                 // 0..15
  const int row  = (((grp << 4) + blk) << 2) + wv; // 0..8191
  const int b    = row >> 10;
  const int s    = (row >> 6) & 15;
  const int c    = CENTERS[s];
  const int lo   = (c - 2 > 0) ? c - 2 : 0;
  const int hi   = (c + 2 < 63) ? c + 2 : 63;
  const int L    = (hi - lo + 1) << 6;
  const size_t vbase = ((size_t)b << 12) + ((size_t)lo << 6);

  const float* srow = S + (size_t)row * NWIN;
  float f[5]; unsigned uo[5];
  #pragma unroll
  for (int j = 0; j < 5; ++j) {
    const int idx = lane + (j << 6);
    const float v = (idx < L) ? srow[idx] : -__builtin_inff();
    f[j] = v;
    const unsigned fb = __float_as_uint(v);
    uo[j] = (fb & 0x80000000u) ? ~fb : (fb | 0x80000000u);  // order-preserving map
  }

  // row max (softmax shift)
  float m = f[0];
  #pragma unroll
  for (int j = 1; j < 5; ++j) m = fmaxf(m, f[j]);
  #pragma unroll
  for (int off = 32; off > 0; off >>= 1) m = fmaxf(m, __shfl_xor(m, off, 64));

  // T = exact 32nd-largest u (greedy MSB radix select; count via ballot+popc)
  unsigned T = 0u;
  for (int bit = 31; bit >= 0; --bit) {
    const unsigned cand = T | (1u << bit);
    int cnt = 0;
    #pragma unroll
    for (int j = 0; j < 5; ++j)
      cnt += __popcll(__ballot(uo[j] >= cand));
    if (cnt >= 32) T = cand;
  }

  // compaction: strict-greater first, then ==T by ascending index (matches lax.top_k)
  int base = 0;
  #pragma unroll
  for (int j = 0; j < 5; ++j) {
    const unsigned long long gm = __ballot(uo[j] > T);
    if (uo[j] > T) {
      const int rank = base + __builtin_amdgcn_mbcnt_hi(
          (unsigned)(gm >> 32), __builtin_amdgcn_mbcnt_lo((unsigned)gm, 0));
      sel_i[wv][rank] = lane + (j << 6);
      sel_p[wv][rank] = __expf(f[j] - m);
    }
    base += __popcll(gm);
  }
  #pragma unroll
  for (int j = 0; j < 5; ++j) {
    const unsigned long long em = __ballot(uo[j] == T);
    if (uo[j] == T) {
      const int er = base + __builtin_amdgcn_mbcnt_hi(
          (unsigned)(em >> 32), __builtin_amdgcn_mbcnt_lo((unsigned)em, 0));
      if (er < 32) {
        sel_i[wv][er] = lane + (j << 6);
        sel_p[wv][er] = __expf(f[j] - m);
      }
    }
    base += __popcll(em);
  }

  // same-wave LDS visibility (lockstep wave; no block barrier needed)
  asm volatile("s_waitcnt lgkmcnt(0)" ::: "memory");

  const int   si = sel_i[wv][lane & 31];
  const float sp = sel_p[wv][lane & 31];
  float dp = (lane < 32) ? sp : 0.f;
  #pragma unroll
  for (int off = 32; off > 0; off >>= 1) dp += __shfl_xor(dp, off, 64);

  // gather: batch 4 t's -> 16 independent loads in flight, then 32 fmas.
  float oacc[8] = {0.f,0.f,0.f,0.f,0.f,0.f,0.f,0.f};
  #pragma unroll
  for (int tb = 0; tb < 32; tb += 4) {
    unsigned raws[4][4];
    #pragma unroll
    for (int q = 0; q < 4; ++q) {
      const int idx_t = __builtin_amdgcn_readlane(si, tb + q);
      const unsigned short* vrow = Vb + ((vbase + (size_t)idx_t) << 9);
      #pragma unroll
      for (int e = 0; e < 4; ++e)
        raws[q][e] = *(const unsigned*)&vrow[(lane << 1) + (e << 7)];
    }
    #pragma unroll
    for (int q = 0; q < 4; ++q) {
      const float p_t = __uint_as_float(
          (unsigned)__builtin_amdgcn_readlane((int)__float_as_uint(sp), tb + q));
      #pragma unroll
      for (int e = 0; e < 4; ++e) {
        oacc[2*e]     = fmaf(p_t, bflo(raws[q][e]), oacc[2*e]);
        oacc[2*e + 1] = fmaf(p_t, bfhi(raws[q][e]), oacc[2*e + 1]);
      }
    }
  }

  const float inv = 1.0f / dp;
  float* orow = O + ((size_t)row << 9);
  #pragma unroll
  for (int e = 0; e < 4; ++e) {
    float2 o2 = make_float2(oacc[2*e] * inv, oacc[2*e + 1] * inv);
    *(float2*)&orow[(lane << 1) + (e << 7)] = o2;
  }
}

// ---------------------------------------------------------------------------------
extern "C" void kernel_launch(void* const* d_in, const int* in_sizes, int n_in,
                              void* d_out, int out_size, void* d_ws, size_t ws_size,
                              hipStream_t stream)
{
  (void)in_sizes; (void)n_in; (void)out_size; (void)ws_size;

  const float* query  = (const float*)d_in[0];
  const float* source = (const float*)d_in[1];
  const float* ctx1   = (const float*)d_in[2];
  const float* ctx2   = (const float*)d_in[3];
  const float* Wq     = (const float*)d_in[4];
  const float* bq     = (const float*)d_in[5];
  const float* Wk     = (const float*)d_in[6];
  // bk (d_in[7]) only contributes row-constant score terms -> provably droppable
  const float* Wv     = (const float*)d_in[8];
  const float* bv     = (const float*)d_in[9];
  const float* Wo     = (const float*)d_in[10];
  const float* bo     = (const float*)d_in[11];
  const float* Wc     = (const float*)d_in[12];
  const float* bc     = (const float*)d_in[13];
  float* out = (float*)d_out;

  // Workspace (~82.1 MB; round 1 proved >= 94.4 MB available):
  char* ws = (char*)d_ws;
  unsigned short* Qgt  = (unsigned short*)(ws);              // 16,777,216 (32 planes x 128 tiles x 4KB)
  unsigned short* v    = (unsigned short*)(ws + 16777216);   // 33,554,432
  float*          S    = (float*)(ws + 50331648);            // 10,485,760
  float*          ctx  = (float*)(ws + 60817408);            // 16,777,216
  unsigned short* Gt   = (unsigned short*)(ws + 77594624);   //  1,048,576
  unsigned short* Wvt  = (unsigned short*)(ws + 78643200);   //    524,288
  unsigned short* Wot  = (unsigned short*)(ws + 79167488);   //    524,288
  float*          gb   = (float*)(ws + 79691776);            //     32,768
  float*          part = (float*)(ws + 79724544);            //    262,144
  float*          u    = (float*)(ws + 79986688);            //      2,048
  unsigned short* Wqh  = (unsigned short*)(ws + 79988736);   //    524,288
  unsigned short* Wql  = (unsigned short*)(ws + 80513024);   //    524,288
  unsigned short* Wkh  = (unsigned short*)(ws + 81037312);   //    524,288
  unsigned short* Wkl  = (unsigned short*)(ws + 81561600);   //    524,288

  // prep1: film_part(256) | u(128) | wsplit(256) | wconv(32) = 672 blocks
  prep1_kernel<<<672, 256, 0, stream>>>(ctx1, ctx2, Wc, part, Wk, bq, u, Wq,
                                        Wqh, Wql, Wkh, Wkl, Wv, Wo, Wvt, Wot);
  // prep2: gmat(256) | film_reduce(32) = 288 blocks
  prep2_kernel<<<288, 256, 0, stream>>>(Wqh, Wql, Wkh, Wkl, Gt, part, bc, gb);
  // QGt = split(FiLM(query) @ G_scaled + u_scaled)  (2-phase prefetch, 512 blocks)
  proj_split<<<512, 256, 0, stream>>>(query, Gt, u, gb, Qgt);
  // v = source @ Wv + bv   (2-phase prefetch, BM=64/BN=512 -- R17-proven)
  proj_v<<<512, 512, 0, stream>>>(source, Wvt, bv, v);
  // windowed scores (2-phase prefetch): A via gload from QGt, B cvt'd from f32 source
  scores_mfma<<<dim3(5, 128), 256, 0, stream>>>(Qgt, source, S);
  // top-32 + softmax + PV  (radix-select, batched gather)
  topk_pv<<<2048, 256, 0, stream>>>(S, v, ctx);
  // out = ctx @ Wo + bo   (2-phase prefetch, 64x128 tile, 512 blocks)
  proj_o<<<512, 256, 0, stream>>>(ctx, Wot, bo, out);
}

// Round 20
// 141.573 us; speedup vs baseline: 1.0516x; 1.0067x over previous
//
#include <hip/hip_runtime.h>

// LocalTopKCrossReadout: B=8, Lq=1024 (16 steps x 64), Lkv=4096 (64 x 64),
// DIM=512, WINDOW=2 (<=5 steps = 320 cols), TOPK=32.
#define NWIN 320
#define SCORE_SCALE 0.04419417382415922f  // 1/sqrt(512)

__constant__ int CENTERS[16] = {0,4,8,13,17,21,25,29,34,38,42,46,50,55,59,63};

typedef __attribute__((ext_vector_type(8))) short v8s;   // 8 bf16
typedef __attribute__((ext_vector_type(4))) float v4f;   // 4 f32 acc

__device__ __forceinline__ float bflo(unsigned u) { return __uint_as_float(u << 16); }
__device__ __forceinline__ float bfhi(unsigned u) { return __uint_as_float(u & 0xffff0000u); }
__device__ __forceinline__ float bf2f(unsigned short h) { return __uint_as_float(((unsigned)h) << 16); }
__device__ __forceinline__ unsigned short f2bf(float x) {
  unsigned u = __float_as_uint(x);
  unsigned r = 0x7fffu + ((u >> 16) & 1u);   // RNE
  return (unsigned short)((u + r) >> 16);
}

// ---- T64 tile: 64 rows x 32 k bf16 in 4096 B, XOR-swizzled for conflict-free b128 ----
__device__ __forceinline__ int t64_off(int r, int k) {
  return ((r & 31) << 7) + (((((r >> 5) << 2) | (k >> 3)) ^ (r & 7)) << 4) + ((k & 7) << 1);
}
__device__ __forceinline__ int frag_off(int r, int g) {
  return ((r & 31) << 7) + (((((r >> 5) << 2) | g) ^ (r & 7)) << 4);
}

__device__ __forceinline__ void gload_lds16(const void* g, void* l) {
  __builtin_amdgcn_global_load_lds((const __attribute__((address_space(1))) unsigned int*)g,
                                   (__attribute__((address_space(3))) unsigned int*)l, 16, 0, 0);
}

// pack 8 f32 -> hi-bf16 plane AND lo-residual plane in one shot
__device__ __forceinline__ void cvt8pair(float4 a, float4 b, uint4& hi4, uint4& lo4) {
  float v[8] = {a.x, a.y, a.z, a.w, b.x, b.y, b.z, b.w};
  unsigned short h[8], l[8];
  #pragma unroll
  for (int e = 0; e < 8; ++e) {
    h[e] = f2bf(v[e]);
    l[e] = f2bf(v[e] - bf2f(h[e]));
  }
  hi4.x = (unsigned)h[0] | ((unsigned)h[1] << 16);
  hi4.y = (unsigned)h[2] | ((unsigned)h[3] << 16);
  hi4.z = (unsigned)h[4] | ((unsigned)h[5] << 16);
  hi4.w = (unsigned)h[6] | ((unsigned)h[7] << 16);
  lo4.x = (unsigned)l[0] | ((unsigned)l[1] << 16);
  lo4.y = (unsigned)l[2] | ((unsigned)l[3] << 16);
  lo4.z = (unsigned)l[4] | ((unsigned)l[5] << 16);
  lo4.w = (unsigned)l[6] | ((unsigned)l[7] << 16);
}

__device__ __forceinline__ uint4 cvt8hi(float4 a, float4 b) {
  uint4 r;
  r.x = (unsigned)f2bf(a.x) | ((unsigned)f2bf(a.y) << 16);
  r.y = (unsigned)f2bf(a.z) | ((unsigned)f2bf(a.w) << 16);
  r.z = (unsigned)f2bf(b.x) | ((unsigned)f2bf(b.y) << 16);
  r.w = (unsigned)f2bf(b.z) | ((unsigned)f2bf(b.w) << 16);
  return r;
}

__device__ __forceinline__ uint2 cvt4(float4 a) {
  uint2 r;
  r.x = (unsigned)f2bf(a.x) | ((unsigned)f2bf(a.y) << 16);
  r.y = (unsigned)f2bf(a.z) | ((unsigned)f2bf(a.w) << 16);
  return r;
}

// ================= prep1: film_part + u + wsplit + wconv (fused, 256 thr) =========
__global__ __launch_bounds__(256) void prep1_kernel(
    const float* __restrict__ ctx1, const float* __restrict__ ctx2,
    const float* __restrict__ Wc,  float* __restrict__ part,
    const float* __restrict__ Wk,  const float* __restrict__ bq, float* __restrict__ u,
    const float* __restrict__ Wq,
    unsigned short* __restrict__ Wqh, unsigned short* __restrict__ Wql,
    unsigned short* __restrict__ Wkh, unsigned short* __restrict__ Wkl,
    const float* __restrict__ Wv, const float* __restrict__ Wo,
    unsigned short* __restrict__ Wvt, unsigned short* __restrict__ Wot)
{
  __shared__ char img[32768];
  const int bid = blockIdx.x;
  const int tid = threadIdx.x;

  if (bid < 256) {
    // ---- film_part: b(8) x sl(8) x jq(4) ----
    const int b = bid >> 5, sl = (bid >> 2) & 7, jq = bid & 3;
    const int j = jq * 256 + tid;
    const int i0 = sl * 128;
    float acc = 0.f;
    #pragma unroll 4
    for (int t = 0; t < 128; ++t) {
      const int i = i0 + t;
      const float f = (i < 512) ? ctx1[b * 512 + i] : ctx2[b * 512 + i - 512];
      acc = fmaf(f, Wc[(size_t)i * 1024 + j], acc);
    }
    part[(b * 8 + sl) * 1024 + j] = acc;
  } else if (bid < 384) {
    // ---- u = (Wk . bq) * scale: 4 d per block (one per wave) ----
    const int d = (bid - 256) * 4 + (tid >> 6);
    const int lane = tid & 63;
    float4 a0 = *(const float4*)&Wk[(size_t)d * 512 + lane * 8];
    float4 a1 = *(const float4*)&Wk[(size_t)d * 512 + lane * 8 + 4];
    float4 c0 = *(const float4*)&bq[lane * 8];
    float4 c1 = *(const float4*)&bq[lane * 8 + 4];
    float s = a0.x*c0.x + a0.y*c0.y + a0.z*c0.z + a0.w*c0.w
            + a1.x*c1.x + a1.y*c1.y + a1.z*c1.z + a1.w*c1.w;
    #pragma unroll
    for (int off = 32; off > 0; off >>= 1) s += __shfl_xor(s, off, 64);
    if (lane == 0) u[d] = s * SCORE_SCALE;
  } else if (bid < 640) {
    // ---- wsplit: Wq/Wk -> row-major bf16 hi/lo planes ----
    const int b = bid - 384;          // 0..255
    const int mat = b >> 7;
    const float* Wsrc = mat ? Wk : Wq;
    unsigned short* Wh = mat ? Wkh : Wqh;
    unsigned short* Wl = mat ? Wkl : Wql;
    const size_t e0 = (((size_t)(b & 127) * 256) + tid) * 8;
    float4 x0 = *(const float4*)&Wsrc[e0];
    float4 x1 = *(const float4*)&Wsrc[e0 + 4];
    uint4 h4, l4;
    cvt8pair(x0, x1, h4, l4);
    *(uint4*)&Wh[e0] = h4;
    *(uint4*)&Wl[e0] = l4;
  } else {
    // ---- wconv: Wv/Wo -> T64 hi tiles (W^T layout) ----
    const int cb = bid - 640;         // 0..31
    const int ktile = cb & 15;
    const int mat   = cb >> 4;
    const float* W = mat ? Wo : Wv;
    unsigned short* Dt = mat ? Wot : Wvt;
    const int k  = tid >> 3;
    const int nt = tid & 7;
    #pragma unroll
    for (int e4 = 0; e4 < 16; ++e4) {
      float4 w = *(const float4*)&W[(size_t)(ktile * 32 + k) * 512 + nt * 64 + e4 * 4];
      float vv[4] = {w.x, w.y, w.z, w.w};
      #pragma unroll
      for (int c = 0; c < 4; ++c) {
        const int n = e4 * 4 + c;
        *(unsigned short*)(img + nt * 4096 + t64_off(n, k)) = f2bf(vv[c]);
      }
    }
    __syncthreads();
    const uint4* src = (const uint4*)img;
    uint4* dst = (uint4*)((char*)Dt + (size_t)ktile * 32768);
    for (int i = tid; i < 2048; i += 256) dst[i] = src[i];
  }
}

// ================= prep2: gmat_mfma + film_reduce (fused, 256 thr) ================
__global__ __launch_bounds__(256) void prep2_kernel(
    const unsigned short* __restrict__ Wqh, const unsigned short* __restrict__ Wql,
    const unsigned short* __restrict__ Wkh, const unsigned short* __restrict__ Wkl,
    unsigned short* __restrict__ Gt,
    const float* __restrict__ part, const float* __restrict__ bc,
    float* __restrict__ gb)
{
  const int bid = blockIdx.x;
  const int tid = threadIdx.x;

  if (bid < 256) {
    // ---- G = (Wq @ Wk^T)*scale via split MFMA -> hi/lo T64 tiles ----
    const int lane = tid & 63, l15 = lane & 15, g = lane >> 4;
    const int wave = tid >> 6;
    const int t  = (bid << 2) | wave;   // 0..1023
    const int ti = t >> 5, tj = t & 31;
    const int ib = ti << 4, jb = tj << 4;
    const size_t arow = (size_t)(ib + l15) * 512 + (g << 3);
    const size_t brow = (size_t)(jb + l15) * 512 + (g << 3);

    v4f acc = (v4f){0.f, 0.f, 0.f, 0.f};
    #pragma unroll 4
    for (int kk = 0; kk < 16; ++kk) {
      const int kd = kk * 32;
      const v8s ah = *(const v8s*)&Wqh[arow + kd];
      const v8s al = *(const v8s*)&Wql[arow + kd];
      const v8s bh = *(const v8s*)&Wkh[brow + kd];
      const v8s bl = *(const v8s*)&Wkl[brow + kd];
      acc = __builtin_amdgcn_mfma_f32_16x16x32_bf16(ah, bh, acc, 0, 0, 0);
      acc = __builtin_amdgcn_mfma_f32_16x16x32_bf16(al, bh, acc, 0, 0, 0);
      acc = __builtin_amdgcn_mfma_f32_16x16x32_bf16(ah, bl, acc, 0, 0, 0);
    }
    #pragma unroll
    for (int k = 0; k < 4; ++k) {
      const int gi = ib + (g << 2) + k;
      const int gj = jb + l15;
      const float v = acc[k] * SCORE_SCALE;
      const unsigned short hi = f2bf(v);
      const unsigned short lo = f2bf(v - bf2f(hi));
      const int toff = t64_off(gj & 63, gi & 31);
      *(unsigned short*)((char*)Gt + ((size_t)((gi >> 5) * 8 + (gj >> 6)) << 12) + toff) = hi;
      *(unsigned short*)((char*)Gt + ((size_t)(((gi >> 5) + 16) * 8 + (gj >> 6)) << 12) + toff) = lo;
    }
  } else {
    // ---- film_reduce: b(8) x jq(4) ----
    const int rb = bid - 256;   // 0..31
    const int b = rb >> 2, jq = rb & 3;
    const int j = jq * 256 + tid;
    float acc = bc[j];
    #pragma unroll
    for (int sl = 0; sl < 8; ++sl) acc += part[(b * 8 + sl) * 1024 + j];
    gb[b * 1024 + j] = acc;
  }
}

// ---------------- qg projection: QGt = split(FiLM(query)@G + u) ----------
// BK=32, 2-phase prefetch; LDS-repack epilogue for coalesced T64 stores.
__global__ __launch_bounds__(256) void proj_split(
    const float* __restrict__ A, const unsigned short* __restrict__ Bt,
    const float* __restrict__ bias, const float* __restrict__ gb,
    unsigned short* __restrict__ Qgt)
{
  __shared__ char smem[49152];   // 2 x { LAh 4K | LAl 4K | LBh 8K | LBl 8K }
  const int tid  = threadIdx.x;
  const int lane = tid & 63, l15 = lane & 15, g = lane >> 4;
  const int wave = tid >> 6, wm = wave >> 1, wn = wave & 1;
  const int bid = blockIdx.x;
  const int xcd = bid & 7, idx = bid >> 3;
  const int mBlk = (idx & 15) | (xcd << 4);   // 0..127
  const int nBlk = idx >> 4;                  // 0..3

  const int sr = tid >> 2;   // 0..63
  const int sq = tid & 3;    // k-octet
  const size_t arow = (size_t)(mBlk * 64 + sr) * 512 + sq * 8;
  const int gbbase = ((mBlk >> 4) * 1024) + sq * 8;
  const int awoff = t64_off(sr, sq * 8);

  int aoff[2], boff[4];
  #pragma unroll
  for (int fm = 0; fm < 2; ++fm) aoff[fm] = frag_off(wm * 32 + fm * 16 + l15, g);
  #pragma unroll
  for (int fn = 0; fn < 4; ++fn) {
    const int n = wn * 64 + fn * 16 + l15;   // 0..127
    boff[fn] = ((n >> 6) << 12) + frag_off(n & 63, g);
  }

  v4f acc[2][4];
  #pragma unroll
  for (int fm = 0; fm < 2; ++fm)
    #pragma unroll
    for (int fn = 0; fn < 4; ++fn) acc[fm][fn] = (v4f){0.f, 0.f, 0.f, 0.f};

  auto stageB = [&](int buf, int tk) {
    const char* gsh = (const char*)Bt + ((size_t)(tk * 8 + nBlk * 2) << 12) + (size_t)tid * 16;
    const char* gsl = (const char*)Bt + ((size_t)((tk + 16) * 8 + nBlk * 2) << 12) + (size_t)tid * 16;
    char* dh = smem + buf * 24576 + 8192 + (wave << 10);
    char* dl = smem + buf * 24576 + 16384 + (wave << 10);
    #pragma unroll
    for (int i = 0; i < 2; ++i) {
      gload_lds16(gsh + i * 4096, dh + i * 4096);
      gload_lds16(gsl + i * 4096, dl + i * 4096);
    }
  };
  auto loadA = [&](int tk, float4* r) {
    const int kd = tk * 32;
    r[0] = *(const float4*)&A[arow + kd];
    r[1] = *(const float4*)&A[arow + kd + 4];
    r[2] = *(const float4*)&gb[gbbase + kd];
    r[3] = *(const float4*)&gb[gbbase + kd + 4];
    r[4] = *(const float4*)&gb[gbbase + 512 + kd];
    r[5] = *(const float4*)&gb[gbbase + 512 + kd + 4];
  };
  auto writeA = [&](int buf, float4* r) {
    float4 x0 = r[0], x1 = r[1];
    x0.x = fmaf(x0.x, 1.f + r[2].x, r[4].x); x0.y = fmaf(x0.y, 1.f + r[2].y, r[4].y);
    x0.z = fmaf(x0.z, 1.f + r[2].z, r[4].z); x0.w = fmaf(x0.w, 1.f + r[2].w, r[4].w);
    x1.x = fmaf(x1.x, 1.f + r[3].x, r[5].x); x1.y = fmaf(x1.y, 1.f + r[3].y, r[5].y);
    x1.z = fmaf(x1.z, 1.f + r[3].z, r[5].z); x1.w = fmaf(x1.w, 1.f + r[3].w, r[5].w);
    uint4 hi4, lo4;
    cvt8pair(x0, x1, hi4, lo4);
    *(uint4*)(smem + buf * 24576 + awoff) = hi4;
    *(uint4*)(smem + buf * 24576 + 4096 + awoff) = lo4;
  };

  // prologue: fully stage tile 0 into buf 0
  float4 pr[6];
  stageB(0, 0);
  loadA(0, pr);
  writeA(0, pr);
  __syncthreads();   // drains vmcnt + lgkmcnt

  for (int tk = 0; tk < 16; ++tk) {
    const int cur = tk & 1;
    if (tk < 15) {               // issue next tile's loads (overlap with MFMA)
      stageB(cur ^ 1, tk + 1);
      loadA(tk + 1, pr);
    }
    const char* base = smem + cur * 24576;
    const v8s ah0 = *(const v8s*)(base + aoff[0]);
    const v8s ah1 = *(const v8s*)(base + aoff[1]);
    const v8s al0 = *(const v8s*)(base + 4096 + aoff[0]);
    const v8s al1 = *(const v8s*)(base + 4096 + aoff[1]);
    #pragma unroll
    for (int fn = 0; fn < 4; ++fn) {
      const v8s bh = *(const v8s*)(base + 8192 + boff[fn]);
      const v8s bl = *(const v8s*)(base + 16384 + boff[fn]);
      acc[0][fn] = __builtin_amdgcn_mfma_f32_16x16x32_bf16(ah0, bh, acc[0][fn], 0, 0, 0);
      acc[1][fn] = __builtin_amdgcn_mfma_f32_16x16x32_bf16(ah1, bh, acc[1][fn], 0, 0, 0);
      acc[0][fn] = __builtin_amdgcn_mfma_f32_16x16x32_bf16(al0, bh, acc[0][fn], 0, 0, 0);
      acc[1][fn] = __builtin_amdgcn_mfma_f32_16x16x32_bf16(al1, bh, acc[1][fn], 0, 0, 0);
      acc[0][fn] = __builtin_amdgcn_mfma_f32_16x16x32_bf16(ah0, bl, acc[0][fn], 0, 0, 0);
      acc[1][fn] = __builtin_amdgcn_mfma_f32_16x16x32_bf16(ah1, bl, acc[1][fn], 0, 0, 0);
    }
    if (tk < 15) writeA(cur ^ 1, pr);   // ds_write after MFMA (T14 split)
    __syncthreads();   // one barrier/iter: next tile ready, this buffer read-closed
  }

  // Epilogue: build 8 x 4KB T64 regions (4 kt x hi/lo) in LDS, then coalesced copy.
  #pragma unroll
  for (int fn = 0; fn < 4; ++fn) {
    const int col = nBlk * 128 + wn * 64 + fn * 16 + l15;   // scores k-dim 0..511
    const float bv = bias[col];
    const int ri = (col >> 5) & 3;   // region index = kt - nBlk*4
    const int kk = col & 31;
    #pragma unroll
    for (int fm = 0; fm < 2; ++fm) {
      const int r0 = wm * 32 + fm * 16 + g * 4;
      #pragma unroll
      for (int k = 0; k < 4; ++k) {
        const float vv = acc[fm][fn][k] + bv;
        const unsigned short hi = f2bf(vv);
        const unsigned short lo = f2bf(vv - bf2f(hi));
        const int toff = t64_off(r0 + k, kk);
        *(unsigned short*)(smem + ri * 4096 + toff) = hi;
        *(unsigned short*)(smem + 16384 + ri * 4096 + toff) = lo;
      }
    }
  }
  __syncthreads();
  #pragma unroll
  for (int rg = 0; rg < 8; ++rg) {
    const int kt = nBlk * 4 + (rg & 3);
    const int plane = rg >> 2;            // 0 = hi, 1 = lo (+16 planes)
    const char* srcp = smem + rg * 4096 + (size_t)tid * 16;
    char* dstp = (char*)Qgt + ((size_t)((plane * 16 + kt) * 128 + mBlk) << 12) + (size_t)tid * 16;
    *(uint4*)dstp = *(const uint4*)srcp;
  }
}

// ---------------- V projection: BM=64, BN=512, 512 thr, 2-phase prefetch ------
// LDS-repack epilogue: acc -> LDS (padded rows) -> coalesced uint4 stores.
__global__ __launch_bounds__(512) void proj_v(
    const float* __restrict__ A, const unsigned short* __restrict__ Bt,
    const float* __restrict__ bias, unsigned short* __restrict__ Cb)
{
  __shared__ char smem[8192 + 65536];   // LA 2x4K | LB 2x32K ; epilogue reuses all
  char* const LA = smem;
  char* const LB = smem + 8192;

  const int tid  = threadIdx.x;
  const int lane = tid & 63, l15 = lane & 15, g = lane >> 4;
  const int wave = tid >> 6, wm = wave >> 2, wn = wave & 3;
  const int mBlk = blockIdx.x;

  const int sr  = tid >> 3;   // 0..63
  const int sq4 = tid & 7;    // k-quad
  const size_t arow = (size_t)(mBlk * 64 + sr) * 512 + sq4 * 4;
  const int awoff = t64_off(sr, sq4 * 4);

  int aoff[2], boff[8];
  #pragma unroll
  for (int fm = 0; fm < 2; ++fm) aoff[fm] = frag_off(wm * 32 + fm * 16 + l15, g);
  #pragma unroll
  for (int fn = 0; fn < 8; ++fn) {
    const int n = wn * 128 + fn * 16 + l15;
    boff[fn] = ((n >> 6) << 12) + frag_off(n & 63, g);
  }

  v4f acc[2][8];
  #pragma unroll
  for (int fm = 0; fm < 2; ++fm)
    #pragma unroll
    for (int fn = 0; fn < 8; ++fn) acc[fm][fn] = (v4f){0.f, 0.f, 0.f, 0.f};

  auto stageB = [&](int buf, int tk) {
    const char* gs = (const char*)Bt + ((size_t)tk << 15) + (wave << 12) + (lane << 4);
    char* ld = LB + (buf << 15) + (wave << 12);
    #pragma unroll
    for (int i = 0; i < 4; ++i) gload_lds16(gs + (i << 10), ld + (i << 10));
  };

  // prologue: fully stage tile 0 into buf 0
  float4 xa = *(const float4*)&A[arow];
  stageB(0, 0);
  *(uint2*)(LA + awoff) = cvt4(xa);
  __syncthreads();

  for (int tk = 0; tk < 16; ++tk) {
    const int cur = tk & 1;
    if (tk < 15) {
      stageB(cur ^ 1, tk + 1);
      xa = *(const float4*)&A[arow + (tk + 1) * 32];
    }
    const v8s a0 = *(const v8s*)(LA + (cur << 12) + aoff[0]);
    const v8s a1 = *(const v8s*)(LA + (cur << 12) + aoff[1]);
    #pragma unroll
    for (int fn = 0; fn < 8; ++fn) {
      const v8s bb = *(const v8s*)(LB + (cur << 15) + boff[fn]);
      acc[0][fn] = __builtin_amdgcn_mfma_f32_16x16x32_bf16(a0, bb, acc[0][fn], 0, 0, 0);
      acc[1][fn] = __builtin_amdgcn_mfma_f32_16x16x32_bf16(a1, bb, acc[1][fn], 0, 0, 0);
    }
    if (tk < 15) *(uint2*)(LA + ((cur ^ 1) << 12) + awoff) = cvt4(xa);
    __syncthreads();
  }

  // Epilogue: repack 64x512 bf16 tile via LDS (row stride 1056 B = bank-spread), then
  // fully-coalesced uint4 stores (16 B/lane).
  #pragma unroll
  for (int fn = 0; fn < 8; ++fn) {
    const int col = wn * 128 + fn * 16 + l15;
    const float bv = bias[col];
    #pragma unroll
    for (int fm = 0; fm < 2; ++fm) {
      const int r0 = wm * 32 + fm * 16 + g * 4;
      #pragma unroll
      for (int k = 0; k < 4; ++k)
        *(unsigned short*)(smem + (r0 + k) * 1056 + col * 2) = f2bf(acc[fm][fn][k] + bv);
    }
  }
  __syncthreads();
  #pragma unroll
  for (int u8 = 0; u8 < 8; ++u8) {
    const int u = u8 * 512 + tid;          // 0..4095 (16-B units of 64 KB tile)
    const int row = u >> 6;
    const int off = (u & 63) * 16;
    const uint4 val = *(const uint4*)(smem + row * 1056 + off);
    *(uint4*)((char*)Cb + (size_t)(mBlk * 64 + row) * 1024 + off) = val;
  }
}

// ---------------- O projection: BM=64, BN=128, grid 512, 2-phase prefetch -------
__global__ __launch_bounds__(256) void proj_o(
    const float* __restrict__ A, const unsigned short* __restrict__ Bt,
    const float* __restrict__ bias, float* __restrict__ Cf)
{
  __shared__ char smem[24576];   // 2 x { LA 4K | LB 8K }
  const int tid  = threadIdx.x;
  const int lane = tid & 63, l15 = lane & 15, g = lane >> 4;
  const int wave = tid >> 6, wm = wave >> 1, wn = wave & 1;
  const int bid = blockIdx.x;
  const int xcd = bid & 7, idx = bid >> 3;
  const int mBlk = (idx & 15) | (xcd << 4);   // 0..127
  const int nBlk = idx >> 4;                  // 0..3

  const int sr = tid >> 2;   // 0..63
  const int sq = tid & 3;    // k-octet
  const size_t arow = (size_t)(mBlk * 64 + sr) * 512 + sq * 8;
  const int awoff = t64_off(sr, sq * 8);

  int aoff[2], boff[4];
  #pragma unroll
  for (int fm = 0; fm < 2; ++fm) aoff[fm] = frag_off(wm * 32 + fm * 16 + l15, g);
  #pragma unroll
  for (int fn = 0; fn < 4; ++fn) {
    const int n = wn * 64 + fn * 16 + l15;
    boff[fn] = ((n >> 6) << 12) + frag_off(n & 63, g);
  }

  v4f acc[2][4];
  #pragma unroll
  for (int fm = 0; fm < 2; ++fm)
    #pragma unroll
    for (int fn = 0; fn < 4; ++fn) acc[fm][fn] = (v4f){0.f, 0.f, 0.f, 0.f};

  auto stageB = [&](int buf, int tk) {
    const char* gs = (const char*)Bt + ((size_t)tk << 15) + ((size_t)nBlk << 13) + (size_t)tid * 16;
    char* ld = smem + buf * 12288 + 4096 + (wave << 10);
    #pragma unroll
    for (int i = 0; i < 2; ++i)
      gload_lds16(gs + i * 4096, ld + i * 4096);
  };

  // prologue
  float4 x0 = *(const float4*)&A[arow];
  float4 x1 = *(const float4*)&A[arow + 4];
  stageB(0, 0);
  *(uint4*)(smem + awoff) = cvt8hi(x0, x1);
  __syncthreads();

  for (int tk = 0; tk < 16; ++tk) {
    const int cur = tk & 1;
    if (tk < 15) {
      stageB(cur ^ 1, tk + 1);
      x0 = *(const float4*)&A[arow + (tk + 1) * 32];
      x1 = *(const float4*)&A[arow + (tk + 1) * 32 + 4];
    }
    const char* base = smem + cur * 12288;
    const v8s a0 = *(const v8s*)(base + aoff[0]);
    const v8s a1 = *(const v8s*)(base + aoff[1]);
    #pragma unroll
    for (int fn = 0; fn < 4; ++fn) {
      const v8s bb = *(const v8s*)(base + 4096 + boff[fn]);
      acc[0][fn] = __builtin_amdgcn_mfma_f32_16x16x32_bf16(a0, bb, acc[0][fn], 0, 0, 0);
      acc[1][fn] = __builtin_amdgcn_mfma_f32_16x16x32_bf16(a1, bb, acc[1][fn], 0, 0, 0);
    }
    if (tk < 15) *(uint4*)(smem + (cur ^ 1) * 12288 + awoff) = cvt8hi(x0, x1);
    __syncthreads();
  }

  #pragma unroll
  for (int fn = 0; fn < 4; ++fn) {
    const int col = nBlk * 128 + wn * 64 + fn * 16 + l15;
    const float bv = bias[col];
    #pragma unroll
    for (int fm = 0; fm < 2; ++fm) {
      const int r0 = mBlk * 64 + wm * 32 + fm * 16 + g * 4;
      #pragma unroll
      for (int k = 0; k < 4; ++k)
        Cf[(size_t)(r0 + k) * 512 + col] = acc[fm][fn][k] + bv;
    }
  }
}

// ---------------- Windowed scores: S = qg' . src^T  (2-phase prefetch) ------
__global__ __launch_bounds__(256) void scores_mfma(
    const unsigned short* __restrict__ Qgt, const float* __restrict__ SRC,
    float* __restrict__ S)
{
  const int bs = blockIdx.y;
  const int s = bs & 15, b = bs >> 4;
  const int c  = CENTERS[s];
  const int lo = (c - 2 > 0) ? c - 2 : 0;
  const int hi = (c + 2 < 63) ? c + 2 : 63;
  if ((int)blockIdx.x > hi - lo) return;

  __shared__ char smem[32768];   // 2 x { LAh 4K | LAl 4K | LBh 4K | LBl 4K }
  const int tid = threadIdx.x;
  const int lane = tid & 63, l15 = lane & 15, g = lane >> 4;
  const int wave = tid >> 6, wm = wave >> 1, wn = wave & 1;
  const int kvrow0 = (b << 12) + ((lo + (int)blockIdx.x) << 6);
  const int qbase  = bs << 6;
  const int sr = tid >> 2, sq = tid & 3;
  const size_t krow = (size_t)(kvrow0 + sr) * 512 + sq * 8;
  const int awoff = t64_off(sr, sq * 8);

  int aoff[2], boff[2];
  #pragma unroll
  for (int f = 0; f < 2; ++f) {
    aoff[f] = frag_off(wm * 32 + f * 16 + l15, g);
    boff[f] = frag_off(wn * 32 + f * 16 + l15, g);
  }

  v4f acc[2][2];
  #pragma unroll
  for (int i = 0; i < 2; ++i)
    #pragma unroll
    for (int j = 0; j < 2; ++j) acc[i][j] = (v4f){0.f, 0.f, 0.f, 0.f};

  auto stageA = [&](int buf, int tk) {
    const char* gah = (const char*)Qgt + ((size_t)(tk * 128 + bs) << 12) + (size_t)tid * 16;
    const char* gal = (const char*)Qgt + ((size_t)((tk + 16) * 128 + bs) << 12) + (size_t)tid * 16;
    gload_lds16(gah, smem + buf * 16384 + (wave << 10));
    gload_lds16(gal, smem + buf * 16384 + 4096 + (wave << 10));
  };
  auto loadB = [&](int tk, float4* r) {
    const int kd = tk * 32;
    r[0] = *(const float4*)&SRC[krow + kd];
    r[1] = *(const float4*)&SRC[krow + kd + 4];
  };
  auto writeB = [&](int buf, float4* r) {
    uint4 bhi, blo;
    cvt8pair(r[0], r[1], bhi, blo);
    *(uint4*)(smem + buf * 16384 + 8192 + awoff) = bhi;
    *(uint4*)(smem + buf * 16384 + 12288 + awoff) = blo;
  };

  // prologue: fully stage tile 0 into buf 0
  float4 pr[2];
  stageA(0, 0);
  loadB(0, pr);
  writeB(0, pr);
  __syncthreads();

  for (int tk = 0; tk < 16; ++tk) {
    const int cur = tk & 1;
    if (tk < 15) {
      stageA(cur ^ 1, tk + 1);
      loadB(tk + 1, pr);
    }
    const char* base = smem + cur * 16384;
    const v8s a0h = *(const v8s*)(base + aoff[0]);
    const v8s a1h = *(const v8s*)(base + aoff[1]);
    const v8s a0l = *(const v8s*)(base + 4096 + aoff[0]);
    const v8s a1l = *(const v8s*)(base + 4096 + aoff[1]);
    const v8s b0h = *(const v8s*)(base + 8192 + boff[0]);
    const v8s b1h = *(const v8s*)(base + 8192 + boff[1]);
    const v8s b0l = *(const v8s*)(base + 12288 + boff[0]);
    const v8s b1l = *(const v8s*)(base + 12288 + boff[1]);
    acc[0][0] = __builtin_amdgcn_mfma_f32_16x16x32_bf16(a0h, b0h, acc[0][0], 0, 0, 0);
    acc[0][1] = __builtin_amdgcn_mfma_f32_16x16x32_bf16(a0h, b1h, acc[0][1], 0, 0, 0);
    acc[1][0] = __builtin_amdgcn_mfma_f32_16x16x32_bf16(a1h, b0h, acc[1][0], 0, 0, 0);
    acc[1][1] = __builtin_amdgcn_mfma_f32_16x16x32_bf16(a1h, b1h, acc[1][1], 0, 0, 0);
    acc[0][0] = __builtin_amdgcn_mfma_f32_16x16x32_bf16(a0l, b0h, acc[0][0], 0, 0, 0);
    acc[0][1] = __builtin_amdgcn_mfma_f32_16x16x32_bf16(a0l, b1h, acc[0][1], 0, 0, 0);
    acc[1][0] = __builtin_amdgcn_mfma_f32_16x16x32_bf16(a1l, b0h, acc[1][0], 0, 0, 0);
    acc[1][1] = __builtin_amdgcn_mfma_f32_16x16x32_bf16(a1l, b1h, acc[1][1], 0, 0, 0);
    acc[0][0] = __builtin_amdgcn_mfma_f32_16x16x32_bf16(a0h, b0l, acc[0][0], 0, 0, 0);
    acc[0][1] = __builtin_amdgcn_mfma_f32_16x16x32_bf16(a0h, b1l, acc[0][1], 0, 0, 0);
    acc[1][0] = __builtin_amdgcn_mfma_f32_16x16x32_bf16(a1h, b0l, acc[1][0], 0, 0, 0);
    acc[1][1] = __builtin_amdgcn_mfma_f32_16x16x32_bf16(a1h, b1l, acc[1][1], 0, 0, 0);
    if (tk < 15) writeB(cur ^ 1, pr);   // ds_write after MFMA (T14 split)
    __syncthreads();
  }

  #pragma unroll
  for (int fn = 0; fn < 2; ++fn) {
    const int cl = wn * 32 + fn * 16 + l15;
    const int colS = ((int)blockIdx.x << 6) + cl;
    #pragma unroll
    for (int fm = 0; fm < 2; ++fm) {
      const int r0 = qbase + wm * 32 + fm * 16 + g * 4;
      #pragma unroll
      for (int k = 0; k < 4; ++k)
        S[(size_t)(r0 + k) * NWIN + colS] = acc[fm][fn][k];
    }
  }
}

// ---------------- Top-32 + softmax + V gather: radix-select, batched gather ------
__global__ __launch_bounds__(256) void topk_pv(
    const float* __restrict__ S, const unsigned short* __restrict__ Vb,
    float* __restrict__ O)
{
  __shared__ int   sel_i[4][32];
  __shared__ float sel_p[4][32];

  const int lane = threadIdx.x & 63;
  const int wv   = threadIdx.x >> 6;
  // XCD-affine bijective remap: the 16 blocks of one step-group share b0&7 -> same XCD
  const int b0   = blockIdx.x;
  const int grp  = (b0 & 7) + ((b0 >> 7) << 3);    // 0..127
  const int blk  = (b0 >> 3) & 15;                 // 0..15
  const int row  = (((grp << 4) + blk) << 2) + wv; // 0..8191
  const int b    = row >> 10;
  const int s    = (row >> 6) & 15;
  const int c    = CENTERS[s];
  const int lo   = (c - 2 > 0) ? c - 2 : 0;
  const int hi   = (c + 2 < 63) ? c + 2 : 63;
  const int L    = (hi - lo + 1) << 6;
  const size_t vbase = ((size_t)b << 12) + ((size_t)lo << 6);

  const float* srow = S + (size_t)row * NWIN;
  float f[5]; unsigned uo[5];
  #pragma unroll
  for (int j = 0; j < 5; ++j) {
    const int idx = lane + (j << 6);
    const float v = (idx < L) ? srow[idx] : -__builtin_inff();
    f[j] = v;
    const unsigned fb = __float_as_uint(v);
    uo[j] = (fb & 0x80000000u) ? ~fb : (fb | 0x80000000u);  // order-preserving map
  }

  // row max (softmax shift)
  float m = f[0];
  #pragma unroll
  for (int j = 1; j < 5; ++j) m = fmaxf(m, f[j]);
  #pragma unroll
  for (int off = 32; off > 0; off >>= 1) m = fmaxf(m, __shfl_xor(m, off, 64));

  // T = exact 32nd-largest u (greedy MSB radix select; count via ballot+popc)
  unsigned T = 0u;
  for (int bit = 31; bit >= 0; --bit) {
    const unsigned cand = T | (1u << bit);
    int cnt = 0;
    #pragma unroll
    for (int j = 0; j < 5; ++j)
      cnt += __popcll(__ballot(uo[j] >= cand));
    if (cnt >= 32) T = cand;
  }

  // compaction: strict-greater first, then ==T by ascending index (matches lax.top_k)
  int base = 0;
  #pragma unroll
  for (int j = 0; j < 5; ++j) {
    const unsigned long long gm = __ballot(uo[j] > T);
    if (uo[j] > T) {
      const int rank = base + __builtin_amdgcn_mbcnt_hi(
          (unsigned)(gm >> 32), __builtin_amdgcn_mbcnt_lo((unsigned)gm, 0));
      sel_i[wv][rank] = lane + (j << 6);
      sel_p[wv][rank] = __expf(f[j] - m);
    }
    base += __popcll(gm);
  }
  #pragma unroll
  for (int j = 0; j < 5; ++j) {
    const unsigned long long em = __ballot(uo[j] == T);
    if (uo[j] == T) {
      const int er = base + __builtin_amdgcn_mbcnt_hi(
          (unsigned)(em >> 32), __builtin_amdgcn_mbcnt_lo((unsigned)em, 0));
      if (er < 32) {
        sel_i[wv][er] = lane + (j << 6);
        sel_p[wv][er] = __expf(f[j] - m);
      }
    }
    base += __popcll(em);
  }

  // same-wave LDS visibility (lockstep wave; no block barrier needed)
  asm volatile("s_waitcnt lgkmcnt(0)" ::: "memory");

  const int   si = sel_i[wv][lane & 31];
  const float sp = sel_p[wv][lane & 31];
  float dp = (lane < 32) ? sp : 0.f;
  #pragma unroll
  for (int off = 32; off > 0; off >>= 1) dp += __shfl_xor(dp, off, 64);

  // gather: batch 4 t's -> 16 independent loads in flight, then 32 fmas.
  float oacc[8] = {0.f,0.f,0.f,0.f,0.f,0.f,0.f,0.f};
  #pragma unroll
  for (int tb = 0; tb < 32; tb += 4) {
    unsigned raws[4][4];
    #pragma unroll
    for (int q = 0; q < 4; ++q) {
      const int idx_t = __builtin_amdgcn_readlane(si, tb + q);
      const unsigned short* vrow = Vb + ((vbase + (size_t)idx_t) << 9);
      #pragma unroll
      for (int e = 0; e < 4; ++e)
        raws[q][e] = *(const unsigned*)&vrow[(lane << 1) + (e << 7)];
    }
    #pragma unroll
    for (int q = 0; q < 4; ++q) {
      const float p_t = __uint_as_float(
          (unsigned)__builtin_amdgcn_readlane((int)__float_as_uint(sp), tb + q));
      #pragma unroll
      for (int e = 0; e < 4; ++e) {
        oacc[2*e]     = fmaf(p_t, bflo(raws[q][e]), oacc[2*e]);
        oacc[2*e + 1] = fmaf(p_t, bfhi(raws[q][e]), oacc[2*e + 1]);
      }
    }
  }

  const float inv = 1.0f / dp;
  float* orow = O + ((size_t)row << 9);
  #pragma unroll
  for (int e = 0; e < 4; ++e) {
    float2 o2 = make_float2(oacc[2*e] * inv, oacc[2*e + 1] * inv);
    *(float2*)&orow[(lane << 1) + (e << 7)] = o2;
  }
}

// ---------------------------------------------------------------------------------
extern "C" void kernel_launch(void* const* d_in, const int* in_sizes, int n_in,
                              void* d_out, int out_size, void* d_ws, size_t ws_size,
                              hipStream_t stream)
{
  (void)in_sizes; (void)n_in; (void)out_size; (void)ws_size;

  const float* query  = (const float*)d_in[0];
  const float* source = (const float*)d_in[1];
  const float* ctx1   = (const float*)d_in[2];
  const float* ctx2   = (const float*)d_in[3];
  const float* Wq     = (const float*)d_in[4];
  const float* bq     = (const float*)d_in[5];
  const float* Wk     = (const float*)d_in[6];
  // bk (d_in[7]) only contributes row-constant score terms -> provably droppable
  const float* Wv     = (const float*)d_in[8];
  const float* bv     = (const float*)d_in[9];
  const float* Wo     = (const float*)d_in[10];
  const float* bo     = (const float*)d_in[11];
  const float* Wc     = (const float*)d_in[12];
  const float* bc     = (const float*)d_in[13];
  float* out = (float*)d_out;

  // Workspace (~82.1 MB; round 1 proved >= 94.4 MB available):
  char* ws = (char*)d_ws;
  unsigned short* Qgt  = (unsigned short*)(ws);              // 16,777,216 (32 planes x 128 tiles x 4KB)
  unsigned short* v    = (unsigned short*)(ws + 16777216);   // 33,554,432
  float*          S    = (float*)(ws + 50331648);            // 10,485,760
  float*          ctx  = (float*)(ws + 60817408);            // 16,777,216
  unsigned short* Gt   = (unsigned short*)(ws + 77594624);   //  1,048,576
  unsigned short* Wvt  = (unsigned short*)(ws + 78643200);   //    524,288
  unsigned short* Wot  = (unsigned short*)(ws + 79167488);   //    524,288
  float*          gb   = (float*)(ws + 79691776);            //     32,768
  float*          part = (float*)(ws + 79724544);            //    262,144
  float*          u    = (float*)(ws + 79986688);            //      2,048
  unsigned short* Wqh  = (unsigned short*)(ws + 79988736);   //    524,288
  unsigned short* Wql  = (unsigned short*)(ws + 80513024);   //    524,288
  unsigned short* Wkh  = (unsigned short*)(ws + 81037312);   //    524,288
  unsigned short* Wkl  = (unsigned short*)(ws + 81561600);   //    524,288

  // prep1: film_part(256) | u(128) | wsplit(256) | wconv(32) = 672 blocks
  prep1_kernel<<<672, 256, 0, stream>>>(ctx1, ctx2, Wc, part, Wk, bq, u, Wq,
                                        Wqh, Wql, Wkh, Wkl, Wv, Wo, Wvt, Wot);
  // prep2: gmat(256) | film_reduce(32) = 288 blocks
  prep2_kernel<<<288, 256, 0, stream>>>(Wqh, Wql, Wkh, Wkl, Gt, part, bc, gb);
  // QGt = split(FiLM(query) @ G_scaled + u_scaled)  (2-phase prefetch + LDS epilogue)
  proj_split<<<512, 256, 0, stream>>>(query, Gt, u, gb, Qgt);
  // v = source @ Wv + bv   (2-phase prefetch + coalesced LDS-repack epilogue)
  proj_v<<<512, 512, 0, stream>>>(source, Wvt, bv, v);
  // windowed scores (2-phase prefetch): A via gload from QGt, B cvt'd from f32 source
  scores_mfma<<<dim3(5, 128), 256, 0, stream>>>(Qgt, source, S);
  // top-32 + softmax + PV  (radix-select, batched gather)
  topk_pv<<<2048, 256, 0, stream>>>(S, v, ctx);
  // out = ctx @ Wo + bo   (2-phase prefetch, 64x128 tile, 512 blocks)
  proj_o<<<512, 256, 0, stream>>>(ctx, Wot, bo, out);
}